// Round 10
// baseline (362.587 us; speedup 1.0000x reference)
//
#include <hip/hip_runtime.h>
#include <cstdint>
#include <cstddef>

typedef unsigned short u16;
typedef short bf16x8 __attribute__((ext_vector_type(8)));
typedef float f32x4 __attribute__((ext_vector_type(4)));

#define MFMA(a,b,c) __builtin_amdgcn_mfma_f32_16x16x32_bf16(a,b,c,0,0,0)

__device__ __forceinline__ u16 f2bf(float f) {
  unsigned u = __builtin_bit_cast(unsigned, f);
  u += 0x7fffu + ((u >> 16) & 1u);
  return (u16)(u >> 16);
}
__device__ __forceinline__ float bf2f(u16 b) {
  return __builtin_bit_cast(float, (unsigned)b << 16);
}
__device__ __forceinline__ float exp2_hw(float x) {
  float r;
  asm("v_exp_f32 %0, %1" : "=v"(r) : "v"(x));
  return r;
}
__device__ __forceinline__ void gl_lds16(const void* g, void* l) {
  __builtin_amdgcn_global_load_lds(
      (const __attribute__((address_space(1))) void*)g,
      (__attribute__((address_space(3))) void*)l, 16, 0, 0);
}
template <int N>
__device__ __forceinline__ void wait_vmcnt() {
  if constexpr (N == 0) asm volatile("s_waitcnt vmcnt(0)" ::: "memory");
  else if constexpr (N == 4) asm volatile("s_waitcnt vmcnt(4)" ::: "memory");
  else if constexpr (N == 8) asm volatile("s_waitcnt vmcnt(8)" ::: "memory");
  else if constexpr (N == 12) asm volatile("s_waitcnt vmcnt(12)" ::: "memory");
}

// ---------------- fused f32 -> bf16 convert for all 5 inputs ----------------
__global__ __launch_bounds__(256) void cvt_all(const float* __restrict__ x,
                                               const float* __restrict__ wq,
                                               const float* __restrict__ wk,
                                               const float* __restrict__ wv,
                                               const float* __restrict__ wo,
                                               u16* __restrict__ xb,
                                               u16* __restrict__ wqkvb,
                                               u16* __restrict__ wob) {
  int idx = (blockIdx.x * 256 + threadIdx.x) * 4;
  const float* src;
  u16* dst;
  if (idx < 8388608) { src = x + idx; dst = xb + idx; }
  else if (idx < 12582912) { src = wq + (idx - 8388608); dst = wqkvb + (idx - 8388608); }
  else if (idx < 13631488) { src = wk + (idx - 12582912); dst = wqkvb + (idx - 8388608); }
  else if (idx < 14680064) { src = wv + (idx - 13631488); dst = wqkvb + (idx - 8388608); }
  else if (idx < 18874368) { src = wo + (idx - 14680064); dst = wob + (idx - 14680064); }
  else return;
  float4 v = *(const float4*)src;
  ushort4 o = {f2bf(v.x), f2bf(v.y), f2bf(v.z), f2bf(v.w)};
  *(ushort4*)dst = o;
}

// ---------------- RoPE cos/sin table: [T=2048][64] f32 ----------------
__global__ __launch_bounds__(256) void rope_table(float* __restrict__ ctab,
                                                  float* __restrict__ stab) {
  int i = blockIdx.x * 256 + threadIdx.x;  // 0 .. 131071
  int t = i >> 6, f = i & 63;
  float inv_freq = powf(10000.0f, -(2.0f * f) / 128.0f);
  float ang = (float)t * inv_freq;
  ctab[i] = cosf(ang);
  stab[i] = sinf(ang);
}

// ---------------- NT GEMM: A via LDS, B streamed through registers from L2 ----------------
// BK=64, A double-buffered in LDS (64KB), B-frags prefetched one tile ahead into
// alternating register sets. Per tile: one 64-MFMA region (compiler-scheduled with
// interleaved ds_reads + global B loads), lgkm0+barrier, stage A(t+2), counted
// vmcnt(12) (retires A(t+1); B(t+1)+A(t+2) stay in flight), barrier.
template <int BM, int BN, int OUT_F32>
__global__ __launch_bounds__(512, 2) void gemm_bs(const u16* __restrict__ A,
                                                  const u16* __restrict__ Bw,
                                                  void* __restrict__ Cout,
                                                  int M, int N, int K) {
  constexpr int WN = BN / 64;            // waves along N (4 or 2)
  constexpr int WM = 8 / WN;             // waves along M
  constexpr int MSUB = BM / WM;          // rows per wave (128 or 64)
  constexpr int MF = MSUB / 16;          // A frags per wave (8 or 4)
  constexpr int APW = BM / 8 / 8;        // A chunks per wave (1KB = 8 rows x 128B)

  __shared__ u16 As[2][BM * 64];         // 128B rows, 3-bit slot XOR swizzle

  const int tid = threadIdx.x;
  const int lane = tid & 63;
  const int wv = tid >> 6;
  const int l16 = lane & 15, lhi = lane >> 4;
  const int wm = wv / WN, wn = wv % WN;
  const int m0 = blockIdx.y * BM;
  const int n0 = blockIdx.x * BN;
  const int nt = K >> 6;

  const int srow8 = lane >> 3;
  const int scol = ((lane & 7) * 16) ^ (srow8 << 4);

  auto stageA = [&](int buf, int kt) {
#pragma unroll
    for (int c = 0; c < APW; ++c) {
      int g = wv + 8 * c;
      int row = m0 + g * 8 + srow8;
      const char* src = (const char*)A + ((size_t)row * K + (size_t)kt * 64) * 2 + scol;
      gl_lds16(src, (char*)As[buf] + g * 1024);
    }
  };
  auto readA = [&](int buf, int mi, int kk) -> bf16x8 {
    int lr = wm * MSUB + mi * 16 + l16;
    return *(const bf16x8*)((const char*)As[buf] + lr * 128 +
                            ((kk * 64 + lhi * 16) ^ ((l16 & 7) << 4)));
  };
  // B frag straight from global (L2-resident): row = n0+wn*64+ni*16+l16, k = kt*64+kk*32+lhi*8
  const u16* bbase = Bw + (size_t)(n0 + wn * 64 + l16) * K + lhi * 8;
  auto loadB = [&](int kt, int ni, int kk) -> bf16x8 {
    return *(const bf16x8*)(bbase + (size_t)(ni * 16) * K + kt * 64 + kk * 32);
  };

  f32x4 acc[MF][4] = {};
  bf16x8 bc[2][4], bn[2][4];

  // prologue: stage A tiles 0,1; load B tile 0
  stageA(0, 0);
  stageA(1, 1);
#pragma unroll
  for (int kk = 0; kk < 2; ++kk)
#pragma unroll
    for (int ni = 0; ni < 4; ++ni) bc[kk][ni] = loadB(0, ni, kk);
  wait_vmcnt<12>();   // A(0) landed; A(1)+B(0) in flight (B gated by reg deps)
  __builtin_amdgcn_sched_barrier(0);
  __builtin_amdgcn_s_barrier();
  __builtin_amdgcn_sched_barrier(0);

  auto body = [&](int t, bf16x8 (*bcur)[4], bf16x8 (*bnext)[4]) {
    const int b = t & 1;
    // prefetch B(t+1) — latency hides under this tile's MFMA region
    if (t + 1 < nt) {
#pragma unroll
      for (int kk = 0; kk < 2; ++kk)
#pragma unroll
        for (int ni = 0; ni < 4; ++ni) bnext[kk][ni] = loadB(t + 1, ni, kk);
    }
    // one big region: 2*MF ds_reads + 64 MFMA, compiler-scheduled
    __builtin_amdgcn_s_setprio(1);
#pragma unroll
    for (int kk = 0; kk < 2; ++kk)
#pragma unroll
      for (int mi = 0; mi < MF; ++mi) {
        bf16x8 a = readA(b, mi, kk);
#pragma unroll
        for (int ni = 0; ni < 4; ++ni)
          acc[mi][ni] = MFMA(a, bcur[kk][ni], acc[mi][ni]);
      }
    __builtin_amdgcn_s_setprio(0);
    asm volatile("s_waitcnt lgkmcnt(0)" ::: "memory");  // all buf-b ds_reads in regs
    __builtin_amdgcn_sched_barrier(0);
    __builtin_amdgcn_s_barrier();                        // all waves done with buf b
    __builtin_amdgcn_sched_barrier(0);
    if (t + 2 < nt) {
      stageA(b, t + 2);                                  // safe overwrite
      wait_vmcnt<12>();    // retire A(t+1); B(t+1) 8 + A(t+2) 4 stay in flight
    } else if (t + 1 < nt) {
      wait_vmcnt<8>();     // tail: retire A(t+1); B(t+1) 8 in flight
    }
    __builtin_amdgcn_sched_barrier(0);
    __builtin_amdgcn_s_barrier();
    __builtin_amdgcn_sched_barrier(0);
  };

  for (int t = 0; t < nt; t += 2) {
    body(t, bc, bn);
    body(t + 1, bn, bc);
  }

  // epilogue
#pragma unroll
  for (int mi = 0; mi < MF; ++mi)
#pragma unroll
    for (int ni = 0; ni < 4; ++ni) {
      int col = n0 + wn * 64 + ni * 16 + l16;
#pragma unroll
      for (int j = 0; j < 4; ++j) {
        int row = m0 + wm * MSUB + mi * 16 + lhi * 4 + j;
        float v = acc[mi][ni][j];
        if (OUT_F32)
          ((float*)Cout)[(size_t)row * N + col] = v;
        else
          ((u16*)Cout)[(size_t)row * N + col] = f2bf(v);
      }
    }
}

// ---------------- RoPE + L2 norm + gamma (vectorized: 4B/lane) ----------------
template <int NH>
__global__ __launch_bounds__(256) void rope_norm(const u16* __restrict__ raw,
                                                 u16* __restrict__ out,
                                                 const float* __restrict__ ctab,
                                                 const float* __restrict__ stab,
                                                 const float* __restrict__ gamma,
                                                 int stride, int coloff, float scale) {
  int gw = blockIdx.x * 4 + (threadIdx.x >> 6);
  int lane = threadIdx.x & 63;
  int h = gw & (NH - 1);
  int bt = gw / NH;               // 0..4095
  int t = bt & 2047, bb = bt >> 11;
  const u16* r = raw + (size_t)bt * stride + coloff + (size_t)h * 128;
  ushort2 own = *(const ushort2*)(r + 2 * lane);
  int pk = __shfl_xor(__builtin_bit_cast(int, own), 32);
  ushort2 par = __builtin_bit_cast(ushort2, pk);
  float x0 = bf2f(own.x), x1 = bf2f(own.y);
  float y0 = bf2f(par.x), y1 = bf2f(par.y);
  int f = (lane & 31) * 2;
  float2 c2 = *(const float2*)(ctab + t * 64 + f);
  float2 s2 = *(const float2*)(stab + t * 64 + f);
  bool hi = lane >= 32;
  float e0 = hi ? (x0 * c2.x + y0 * s2.x) : (x0 * c2.x - y0 * s2.x);
  float e1 = hi ? (x1 * c2.y + y1 * s2.y) : (x1 * c2.y - y1 * s2.y);
  float ss = e0 * e0 + e1 * e1;
#pragma unroll
  for (int off = 1; off < 64; off <<= 1) ss += __shfl_xor(ss, off);
  float inv = scale / (sqrtf(ss) + 1e-6f);
  float2 g2 = *(const float2*)(gamma + 2 * lane);
  size_t ob = (((size_t)(bb * NH + h)) * 2048 + t) * 128 + 2 * lane;
  ushort2 o = {f2bf(e0 * inv * g2.x), f2bf(e1 * inv * g2.y)};
  *(ushort2*)(out + ob) = o;
}

// ---------------- V transpose: qkv[B*T,3072] cols 2560.. -> [B, HK, 128, T] ----------------
__global__ __launch_bounds__(256) void transpose_v(const u16* __restrict__ qkv,
                                                   u16* __restrict__ vt) {
  __shared__ u16 tile[32][33];
  int t0 = blockIdx.x * 32, d0 = blockIdx.y * 32;
  int bh = blockIdx.z;
  int b = bh >> 2, hkk = bh & 3;
  int tx = threadIdx.x & 31, ty = threadIdx.x >> 5;  // ty 0..7
#pragma unroll
  for (int i = 0; i < 4; ++i) {
    int r = ty + i * 8;
    tile[r][tx] = qkv[((size_t)(b * 2048 + t0 + r)) * 3072 + 2560 + hkk * 128 + d0 + tx];
  }
  __syncthreads();
#pragma unroll
  for (int i = 0; i < 4; ++i) {
    int r = ty + i * 8;
    vt[((size_t)((b * 4 + hkk) * 128 + d0 + r)) * 2048 + t0 + tx] = tile[tx][r];
  }
}

// ---------------- flash attention, sliding window 1024, QBLK=128, KVBLK=64 ----------------
// 8 waves/block (512 thr), K+V double-buffered (swizzled) in LDS, counted-vmcnt
// gates (no vmcnt(0) drain mid-loop), log2-domain softmax with wave-shared base,
// rowsum via ones-MFMA, XCD-aware block remap.
__global__ __launch_bounds__(512, 4) void attn_kernel(const u16* __restrict__ Qr,
                                                      const u16* __restrict__ Kr,
                                                      const u16* __restrict__ Vt,
                                                      u16* __restrict__ Yt) {
  __shared__ u16 Ks[2][64 * 128];   // XOR-swizzled 256B rows (2x16KB)
  __shared__ u16 Vs[2][128 * 64];   // XOR-swizzled 128B rows, [d][s] (2x16KB)
  __shared__ u16 Ps[8][16 * 64];    // per-wave P, XOR-swizzled 128B rows (16KB)
  const int tid = threadIdx.x;
  const int lane = tid & 63;
  const int wv = tid >> 6;          // 0..7
  const int l16 = lane & 15, lhi = lane >> 4;
  const int work = (blockIdx.x & 7) * 64 + (blockIdx.x >> 3);
  const int q0b = (work & 15) << 7;     // q-tile * 128
  const int bh = work >> 4;             // 0..31
  const int b = bh >> 4, h = bh & 15;
  const int hk = h >> 2;
  const int q0w = q0b + wv * 16;

  const u16* qbase = Qr + (((size_t)bh) * 2048 + q0w + l16) * 128;
  bf16x8 qf[4];
#pragma unroll
  for (int dc = 0; dc < 4; ++dc)
    qf[dc] = *(const bf16x8*)(qbase + dc * 32 + lhi * 8);

  const char* kg = (const char*)(Kr + ((size_t)(b * 4 + hk)) * 2048 * 128);
  const u16* vg = Vt + ((size_t)(b * 4 + hk)) * 2048 * 128;  // [128][2048]

  auto stage = [&](int buf, int s0) {   // 4 gl_lds per wave
#pragma unroll
    for (int i = 0; i < 2; ++i) {
      int c = wv + 8 * i;
      int row = c * 4 + lhi;
      int srcb = (l16 * 16) ^ ((row & 7) << 4);
      gl_lds16(kg + (size_t)(s0 + row) * 256 + srcb, (char*)Ks[buf] + c * 1024);
    }
    int r8 = lane >> 3, c8 = lane & 7;
#pragma unroll
    for (int i = 0; i < 2; ++i) {
      int c = wv + 8 * i;
      int row = c * 8 + r8;
      int srcb = (c8 * 16) ^ ((r8 & 7) << 4);
      gl_lds16((const char*)(vg + (size_t)row * 2048 + s0) + srcb,
               (char*)Vs[buf] + c * 1024);
    }
  };

  const bf16x8 ones = {0x3F80, 0x3F80, 0x3F80, 0x3F80, 0x3F80, 0x3F80, 0x3F80, 0x3F80};
  float mbase = 0.f;                // wave-shared log2-domain base
  f32x4 lacc = {};
  f32x4 oacc[8] = {};

  int s_lo = q0b - 1024; if (s_lo < 0) s_lo = 0;
  const int nt = (q0b + 128 - s_lo) >> 6;

  stage(0, s_lo);
  int cur = 0;
  for (int it = 0; it < nt; ++it) {
    const int s0 = s_lo + (it << 6);
    if (it + 1 < nt) {
      stage(cur ^ 1, s0 + 64);
      wait_vmcnt<4>();
    } else {
      wait_vmcnt<0>();
    }
    __builtin_amdgcn_sched_barrier(0);
    __builtin_amdgcn_s_barrier();
    __builtin_amdgcn_sched_barrier(0);
    const bool skip = (q0w + 15 < s0) || (q0w - (s0 + 63) > 1024);
    if (!skip) {
      // QK^T (16 MFMA)
      f32x4 sacc[4] = {};
      const char* ksb = (const char*)Ks[cur];
      __builtin_amdgcn_s_setprio(1);
#pragma unroll
      for (int n = 0; n < 4; ++n) {
        int row = n * 16 + l16;
#pragma unroll
        for (int dc = 0; dc < 4; ++dc) {
          bf16x8 kf = *(const bf16x8*)(ksb + row * 256 +
                                       ((dc * 64 + lhi * 16) ^ ((l16 & 7) << 4)));
          sacc[n] = MFMA(qf[dc], kf, sacc[n]);
        }
      }
      __builtin_amdgcn_s_setprio(0);
      const bool domask = (q0w < s0 + 63) || (q0w + 15 - s0 > 1024);
      if (domask) {
#pragma unroll
        for (int n = 0; n < 4; ++n)
#pragma unroll
          for (int j = 0; j < 4; ++j) {
            int q = q0w + lhi * 4 + j;
            int s = s0 + n * 16 + l16;
            if ((unsigned)(q - s) > 1024u) sacc[n][j] = -INFINITY;
          }
      }
      float mt = sacc[0][0];
#pragma unroll
      for (int n = 0; n < 4; ++n)
#pragma unroll
        for (int j = 0; j < 4; ++j) mt = fmaxf(mt, sacc[n][j]);
#pragma unroll
      for (int off = 1; off < 64; off <<= 1) mt = fmaxf(mt, __shfl_xor(mt, off));
      if (mt > mbase + 8.f) {
        float sc2 = exp2_hw(mbase - mt);
#pragma unroll
        for (int j = 0; j < 4; ++j) lacc[j] *= sc2;
#pragma unroll
        for (int dt = 0; dt < 8; ++dt)
#pragma unroll
          for (int j = 0; j < 4; ++j) oacc[dt][j] *= sc2;
        mbase = mt;
      }
      char* psb = (char*)Ps[wv];
#pragma unroll
      for (int n = 0; n < 4; ++n)
#pragma unroll
        for (int j = 0; j < 4; ++j) {
          float p = exp2_hw(sacc[n][j] - mbase);
          int R = lhi * 4 + j;
          *(u16*)(psb + R * 128 + (((n * 16 + l16) * 2) ^ ((R & 7) << 4))) = f2bf(p);
        }
      bf16x8 pf[2];
#pragma unroll
      for (int kk = 0; kk < 2; ++kk)
        pf[kk] = *(const bf16x8*)(psb + l16 * 128 +
                                  ((kk * 64 + lhi * 16) ^ ((l16 & 7) << 4)));
      const char* vsb = (const char*)Vs[cur];
      __builtin_amdgcn_s_setprio(1);
      lacc = MFMA(pf[0], ones, lacc);
      lacc = MFMA(pf[1], ones, lacc);
#pragma unroll
      for (int dt = 0; dt < 8; ++dt) {
        int row = dt * 16 + l16;
#pragma unroll
        for (int kk = 0; kk < 2; ++kk) {
          bf16x8 vf = *(const bf16x8*)(vsb + row * 128 +
                                       ((kk * 64 + lhi * 16) ^ ((l16 & 7) << 4)));
          oacc[dt] = MFMA(pf[kk], vf, oacc[dt]);
        }
      }
      __builtin_amdgcn_s_setprio(0);
    }
    __builtin_amdgcn_sched_barrier(0);
    __builtin_amdgcn_s_barrier();
    __builtin_amdgcn_sched_barrier(0);
    cur ^= 1;
  }
#pragma unroll
  for (int j = 0; j < 4; ++j) {
    float inv = 1.0f / lacc[j];
    int q = q0w + lhi * 4 + j;
    size_t rowbase = ((size_t)(b * 2048 + q)) * 2048 + (size_t)h * 128;
#pragma unroll
    for (int dt = 0; dt < 8; ++dt)
      Yt[rowbase + dt * 16 + l16] = f2bf(oacc[dt][j] * inv);
  }
}

extern "C" void kernel_launch(void* const* d_in, const int* in_sizes, int n_in,
                              void* d_out, int out_size, void* d_ws, size_t ws_size,
                              hipStream_t stream) {
  (void)in_sizes; (void)n_in; (void)out_size; (void)ws_size;
  const float* x  = (const float*)d_in[0];
  const float* wq = (const float*)d_in[1];
  const float* wk = (const float*)d_in[2];
  const float* wv = (const float*)d_in[3];
  const float* wo = (const float*)d_in[4];
  const float* gq = (const float*)d_in[5];
  const float* gk = (const float*)d_in[6];
  float* out = (float*)d_out;
  char* ws = (char*)d_ws;

  size_t off = 0;
  auto alloc = [&](size_t bytes) {
    size_t o = off;
    off += (bytes + 255) & ~(size_t)255;
    return o;
  };
  u16* xb     = (u16*)(ws + alloc((size_t)4096 * 2048 * 2));
  u16* wqkvb  = (u16*)(ws + alloc((size_t)3072 * 2048 * 2));
  u16* wob    = (u16*)(ws + alloc((size_t)2048 * 2048 * 2));
  u16* qkvraw = (u16*)(ws + alloc((size_t)4096 * 3072 * 2));  // later reused as ytmp
  u16* qr     = (u16*)(ws + alloc((size_t)4096 * 2048 * 2));
  u16* kr     = (u16*)(ws + alloc((size_t)4096 * 512 * 2));
  u16* vt     = (u16*)(ws + alloc((size_t)4096 * 512 * 2));
  float* ctab = (float*)(ws + alloc((size_t)2048 * 64 * 4));
  float* stab = (float*)(ws + alloc((size_t)2048 * 64 * 4));
  u16* ytmp = qkvraw;  // safe: qkvraw fully consumed before attn writes

  // 1/sqrt(128) * log2(e): Q scale folded so scores are in log2 domain
  const float sc_log2 = 0.12751744f;

  cvt_all<<<18432, 256, 0, stream>>>(x, wq, wk, wv, wo, xb, wqkvb, wob);
  rope_table<<<512, 256, 0, stream>>>(ctab, stab);

  // fused QKV projection: [4096,2048] x [3072,2048]^T -> [4096,3072]
  gemm_bs<256, 256, 0><<<dim3(12, 16), 512, 0, stream>>>(xb, wqkvb, qkvraw, 4096, 3072, 2048);

  rope_norm<16><<<16384, 256, 0, stream>>>(qkvraw, qr, ctab, stab, gq, 3072, 0, sc_log2);
  rope_norm<4><<<4096, 256, 0, stream>>>(qkvraw, kr, ctab, stab, gk, 3072, 2048, 1.0f);
  transpose_v<<<dim3(64, 4, 8), 256, 0, stream>>>(qkvraw, vt);

  attn_kernel<<<dim3(512), 512, 0, stream>>>(qr, kr, vt, ytmp);

  // output projection (f32 out): 256x128 tiles -> 256 blocks (1/CU)
  gemm_bs<256, 128, 1><<<dim3(16, 16), 512, 0, stream>>>(ytmp, wob, out, 4096, 2048, 2048);
}

// Round 11
// 311.102 us; speedup vs baseline: 1.1655x; 1.1655x over previous
//
#include <hip/hip_runtime.h>
#include <cstdint>
#include <cstddef>

typedef unsigned short u16;
typedef short bf16x8 __attribute__((ext_vector_type(8)));
typedef float f32x4 __attribute__((ext_vector_type(4)));

#define MFMA(a,b,c) __builtin_amdgcn_mfma_f32_16x16x32_bf16(a,b,c,0,0,0)

__device__ __forceinline__ u16 f2bf(float f) {
  unsigned u = __builtin_bit_cast(unsigned, f);
  u += 0x7fffu + ((u >> 16) & 1u);
  return (u16)(u >> 16);
}
__device__ __forceinline__ float bf2f(u16 b) {
  return __builtin_bit_cast(float, (unsigned)b << 16);
}
__device__ __forceinline__ float exp2_hw(float x) {
  float r;
  asm("v_exp_f32 %0, %1" : "=v"(r) : "v"(x));
  return r;
}
__device__ __forceinline__ void gl_lds16(const void* g, void* l) {
  __builtin_amdgcn_global_load_lds(
      (const __attribute__((address_space(1))) void*)g,
      (__attribute__((address_space(3))) void*)l, 16, 0, 0);
}
template <int N>
__device__ __forceinline__ void wait_vmcnt() {
  if constexpr (N == 0) asm volatile("s_waitcnt vmcnt(0)" ::: "memory");
  else if constexpr (N == 2) asm volatile("s_waitcnt vmcnt(2)" ::: "memory");
  else if constexpr (N == 4) asm volatile("s_waitcnt vmcnt(4)" ::: "memory");
  else if constexpr (N == 6) asm volatile("s_waitcnt vmcnt(6)" ::: "memory");
  else if constexpr (N == 8) asm volatile("s_waitcnt vmcnt(8)" ::: "memory");
}
__device__ __forceinline__ void lgkm0_fence() {
  asm volatile("s_waitcnt lgkmcnt(0)" ::: "memory");
  __builtin_amdgcn_sched_barrier(0);
}
__device__ __forceinline__ void block_barrier() {
  __builtin_amdgcn_sched_barrier(0);
  __builtin_amdgcn_s_barrier();
  __builtin_amdgcn_sched_barrier(0);
}

// ---------------- fused f32 -> bf16 convert for all 5 inputs ----------------
__global__ __launch_bounds__(256) void cvt_all(const float* __restrict__ x,
                                               const float* __restrict__ wq,
                                               const float* __restrict__ wk,
                                               const float* __restrict__ wv,
                                               const float* __restrict__ wo,
                                               u16* __restrict__ xb,
                                               u16* __restrict__ wqkvb,
                                               u16* __restrict__ wob) {
  int idx = (blockIdx.x * 256 + threadIdx.x) * 4;
  const float* src;
  u16* dst;
  if (idx < 8388608) { src = x + idx; dst = xb + idx; }
  else if (idx < 12582912) { src = wq + (idx - 8388608); dst = wqkvb + (idx - 8388608); }
  else if (idx < 13631488) { src = wk + (idx - 12582912); dst = wqkvb + (idx - 8388608); }
  else if (idx < 14680064) { src = wv + (idx - 13631488); dst = wqkvb + (idx - 8388608); }
  else if (idx < 18874368) { src = wo + (idx - 14680064); dst = wob + (idx - 14680064); }
  else return;
  float4 v = *(const float4*)src;
  ushort4 o = {f2bf(v.x), f2bf(v.y), f2bf(v.z), f2bf(v.w)};
  *(ushort4*)dst = o;
}

// ---------------- RoPE cos/sin table: [T=2048][64] f32 ----------------
__global__ __launch_bounds__(256) void rope_table(float* __restrict__ ctab,
                                                  float* __restrict__ stab) {
  int i = blockIdx.x * 256 + threadIdx.x;  // 0 .. 131071
  int t = i >> 6, f = i & 63;
  float inv_freq = powf(10000.0f, -(2.0f * f) / 128.0f);
  float ang = (float)t * inv_freq;
  ctab[i] = cosf(ang);
  stab[i] = sinf(ang);
}

// ============ QKV GEMM: 256x256 tile, BK=64, 4 phases/tile, counted vmcnt ============
// 8 waves (2M x 4N), per-wave 128x64 output. LDS 128KB (A 64K + B 64K, 2 bufs).
// Per phase: stage 2 chunks of tile t+1 -> vmcnt gate -> barrier -> ds_reads ->
// lgkm0 -> 16 MFMA. Slots: s0 B{wv,wv+8} s1 B{wv+16,wv+24} s2 A{wv,wv+16} s3 A{wv+8,wv+24}.
__global__ __launch_bounds__(512, 2) void gemm_q(const u16* __restrict__ A,
                                                 const u16* __restrict__ Bw,
                                                 u16* __restrict__ Cout,
                                                 int M, int N, int K) {
  __shared__ u16 As[2][256 * 64];
  __shared__ u16 Bs[2][256 * 64];
  const int tid = threadIdx.x;
  const int lane = tid & 63;
  const int wv = tid >> 6;
  const int l16 = lane & 15, lhi = lane >> 4;
  const int wm = wv >> 2, wn = wv & 3;
  const int m0 = blockIdx.y * 256;
  const int n0 = blockIdx.x * 256;
  const int nt = K >> 6;

  const int srow8 = lane >> 3;
  const int scol = ((lane & 7) * 16) ^ (srow8 << 4);

  auto stA = [&](int buf, int kt, int g) {
    int row = m0 + g * 8 + srow8;
    const char* src = (const char*)A + ((size_t)row * K + (size_t)kt * 64) * 2 + scol;
    gl_lds16(src, (char*)As[buf] + g * 1024);
  };
  auto stB = [&](int buf, int kt, int g) {
    int row = n0 + g * 8 + srow8;
    const char* src = (const char*)Bw + ((size_t)row * K + (size_t)kt * 64) * 2 + scol;
    gl_lds16(src, (char*)Bs[buf] + g * 1024);
  };
  auto rdA = [&](int buf, int mi, int kk) -> bf16x8 {
    int row = wm * 128 + mi * 16 + l16;
    return *(const bf16x8*)((const char*)As[buf] + row * 128 +
                            ((kk * 64 + lhi * 16) ^ ((l16 & 7) << 4)));
  };
  auto rdB = [&](int buf, int ni, int kk) -> bf16x8 {
    int row = wn * 64 + ni * 16 + l16;
    return *(const bf16x8*)((const char*)Bs[buf] + row * 128 +
                            ((kk * 64 + lhi * 16) ^ ((l16 & 7) << 4)));
  };

  f32x4 acc[8][4] = {};

  // prologue: tile0 fully, tile1 in slot order (FIFO matters)
  stB(0, 0, wv); stB(0, 0, wv + 8); stB(0, 0, wv + 16); stB(0, 0, wv + 24);
  stA(0, 0, wv); stA(0, 0, wv + 16); stA(0, 0, wv + 8); stA(0, 0, wv + 24);
  stB(1, 1, wv); stB(1, 1, wv + 8);      // s0
  stB(1, 1, wv + 16); stB(1, 1, wv + 24);// s1
  stA(1, 1, wv); stA(1, 1, wv + 16);     // s2
  stA(1, 1, wv + 8); stA(1, 1, wv + 24); // s3

  for (int t = 0; t < nt; ++t) {
    const int b = t & 1, ob = b ^ 1;
    const bool st = (t >= 1) && (t + 1 < nt);
    const bool last = (t == nt - 1);
    bf16x8 bf[2][4], af[2][2];

    // ---- ph0 ----
    if (st) { stB(ob, t + 1, wv); stB(ob, t + 1, wv + 8); }
    if (last) wait_vmcnt<2>(); else if (t == 0) wait_vmcnt<8>(); else wait_vmcnt<4>();
    block_barrier();
#pragma unroll
    for (int kk = 0; kk < 2; ++kk)
#pragma unroll
      for (int ni = 0; ni < 4; ++ni) bf[kk][ni] = rdB(b, ni, kk);
#pragma unroll
    for (int kk = 0; kk < 2; ++kk) { af[0][kk] = rdA(b, 0, kk); af[1][kk] = rdA(b, 1, kk); }
    lgkm0_fence();
    __builtin_amdgcn_s_setprio(1);
#pragma unroll
    for (int mi = 0; mi < 2; ++mi)
#pragma unroll
      for (int kk = 0; kk < 2; ++kk)
#pragma unroll
        for (int ni = 0; ni < 4; ++ni)
          acc[mi][ni] = MFMA(af[mi][kk], bf[kk][ni], acc[mi][ni]);
    __builtin_amdgcn_s_setprio(0);

    // ---- ph1..ph3 ----
#pragma unroll
    for (int q = 1; q < 4; ++q) {
      if (st) {
        if (q == 1) { stB(ob, t + 1, wv + 16); stB(ob, t + 1, wv + 24); }
        else if (q == 2) { stA(ob, t + 1, wv); stA(ob, t + 1, wv + 16); }
        else { stA(ob, t + 1, wv + 8); stA(ob, t + 1, wv + 24); }
      }
      if (last) { if (q < 2) wait_vmcnt<2>(); else wait_vmcnt<0>(); }
      else if (t == 0) wait_vmcnt<8>();
      else wait_vmcnt<4>();
      block_barrier();
#pragma unroll
      for (int kk = 0; kk < 2; ++kk) {
        af[0][kk] = rdA(b, 2 * q, kk);
        af[1][kk] = rdA(b, 2 * q + 1, kk);
      }
      lgkm0_fence();
      __builtin_amdgcn_s_setprio(1);
#pragma unroll
      for (int mi = 0; mi < 2; ++mi)
#pragma unroll
        for (int kk = 0; kk < 2; ++kk)
#pragma unroll
          for (int ni = 0; ni < 4; ++ni)
            acc[2 * q + mi][ni] = MFMA(af[mi][kk], bf[kk][ni], acc[2 * q + mi][ni]);
      __builtin_amdgcn_s_setprio(0);
    }
    block_barrier();   // tile end: all waves' reads of buf b complete
  }

  // epilogue (bf16 out)
#pragma unroll
  for (int mi = 0; mi < 8; ++mi)
#pragma unroll
    for (int ni = 0; ni < 4; ++ni) {
      int col = n0 + wn * 64 + ni * 16 + l16;
#pragma unroll
      for (int j = 0; j < 4; ++j) {
        int row = m0 + wm * 128 + mi * 16 + lhi * 4 + j;
        Cout[(size_t)row * N + col] = f2bf(acc[mi][ni][j]);
      }
    }
}

// ============ WO GEMM: 256x128 tile, BK=64, 2 phases/tile, counted vmcnt ============
// 8 waves (4M x 2N), per-wave 64x64 output. LDS 96KB. Slots (4,2), vmcnt(6).
__global__ __launch_bounds__(512, 2) void gemm_o(const u16* __restrict__ A,
                                                 const u16* __restrict__ Bw,
                                                 float* __restrict__ Cout,
                                                 int M, int N, int K) {
  __shared__ u16 As[2][256 * 64];
  __shared__ u16 Bs[2][128 * 64];
  const int tid = threadIdx.x;
  const int lane = tid & 63;
  const int wv = tid >> 6;
  const int l16 = lane & 15, lhi = lane >> 4;
  const int wm = wv >> 1, wn = wv & 1;
  const int m0 = blockIdx.y * 256;
  const int n0 = blockIdx.x * 128;
  const int nt = K >> 6;

  const int srow8 = lane >> 3;
  const int scol = ((lane & 7) * 16) ^ (srow8 << 4);

  auto stA = [&](int buf, int kt, int g) {
    int row = m0 + g * 8 + srow8;
    const char* src = (const char*)A + ((size_t)row * K + (size_t)kt * 64) * 2 + scol;
    gl_lds16(src, (char*)As[buf] + g * 1024);
  };
  auto stB = [&](int buf, int kt, int g) {
    int row = n0 + g * 8 + srow8;
    const char* src = (const char*)Bw + ((size_t)row * K + (size_t)kt * 64) * 2 + scol;
    gl_lds16(src, (char*)Bs[buf] + g * 1024);
  };
  auto rdA = [&](int buf, int mi, int kk) -> bf16x8 {
    int row = wm * 64 + mi * 16 + l16;
    return *(const bf16x8*)((const char*)As[buf] + row * 128 +
                            ((kk * 64 + lhi * 16) ^ ((l16 & 7) << 4)));
  };
  auto rdB = [&](int buf, int ni, int kk) -> bf16x8 {
    int row = wn * 64 + ni * 16 + l16;
    return *(const bf16x8*)((const char*)Bs[buf] + row * 128 +
                            ((kk * 64 + lhi * 16) ^ ((l16 & 7) << 4)));
  };

  // per-wave A-chunk ownership: 2 class0 (read ph0) + 2 class1 (read ph1)
  const int c0a = (wv & 3) + (wv >> 2) * 8;   // class0
  const int c0b = c0a + 16;                   // class0
  const int c1a = c0a + 4;                    // class1
  const int c1b = c0a + 20;                   // class1

  f32x4 acc[4][4] = {};

  // prologue: tile0 fully, tile1 slot-ordered (s0: B,B,c0a,c0b ; s1: c1a,c1b)
  stB(0, 0, wv); stB(0, 0, wv + 8); stA(0, 0, c0a); stA(0, 0, c0b);
  stA(0, 0, c1a); stA(0, 0, c1b);
  stB(1, 1, wv); stB(1, 1, wv + 8); stA(1, 1, c0a); stA(1, 1, c0b); // s0
  stA(1, 1, c1a); stA(1, 1, c1b);                                   // s1

  for (int t = 0; t < nt; ++t) {
    const int b = t & 1, ob = b ^ 1;
    const bool st = (t >= 1) && (t + 1 < nt);
    const bool last = (t == nt - 1);
    bf16x8 bf[2][4], af[2][2];

    // ---- ph0 ----
    if (st) { stB(ob, t + 1, wv); stB(ob, t + 1, wv + 8); stA(ob, t + 1, c0a); stA(ob, t + 1, c0b); }
    if (last) wait_vmcnt<2>(); else wait_vmcnt<6>();
    block_barrier();
#pragma unroll
    for (int kk = 0; kk < 2; ++kk)
#pragma unroll
      for (int ni = 0; ni < 4; ++ni) bf[kk][ni] = rdB(b, ni, kk);
#pragma unroll
    for (int kk = 0; kk < 2; ++kk) { af[0][kk] = rdA(b, 0, kk); af[1][kk] = rdA(b, 1, kk); }
    lgkm0_fence();
    __builtin_amdgcn_s_setprio(1);
#pragma unroll
    for (int mi = 0; mi < 2; ++mi)
#pragma unroll
      for (int kk = 0; kk < 2; ++kk)
#pragma unroll
        for (int ni = 0; ni < 4; ++ni)
          acc[mi][ni] = MFMA(af[mi][kk], bf[kk][ni], acc[mi][ni]);
    __builtin_amdgcn_s_setprio(0);

    // ---- ph1 ----
    if (st) { stA(ob, t + 1, c1a); stA(ob, t + 1, c1b); }
    if (last) wait_vmcnt<0>(); else wait_vmcnt<6>();
    block_barrier();
#pragma unroll
    for (int kk = 0; kk < 2; ++kk) { af[0][kk] = rdA(b, 2, kk); af[1][kk] = rdA(b, 3, kk); }
    lgkm0_fence();
    __builtin_amdgcn_s_setprio(1);
#pragma unroll
    for (int mi = 0; mi < 2; ++mi)
#pragma unroll
      for (int kk = 0; kk < 2; ++kk)
#pragma unroll
        for (int ni = 0; ni < 4; ++ni)
          acc[2 + mi][ni] = MFMA(af[mi][kk], bf[kk][ni], acc[2 + mi][ni]);
    __builtin_amdgcn_s_setprio(0);
    block_barrier();   // tile end
  }

#pragma unroll
  for (int mi = 0; mi < 4; ++mi)
#pragma unroll
    for (int ni = 0; ni < 4; ++ni) {
      int col = n0 + wn * 64 + ni * 16 + l16;
#pragma unroll
      for (int j = 0; j < 4; ++j) {
        int row = m0 + wm * 64 + mi * 16 + lhi * 4 + j;
        Cout[(size_t)row * N + col] = acc[mi][ni][j];
      }
    }
}

// ---------------- RoPE + L2 norm + gamma (vectorized: 4B/lane) ----------------
template <int NH>
__global__ __launch_bounds__(256) void rope_norm(const u16* __restrict__ raw,
                                                 u16* __restrict__ out,
                                                 const float* __restrict__ ctab,
                                                 const float* __restrict__ stab,
                                                 const float* __restrict__ gamma,
                                                 int stride, int coloff, float scale) {
  int gw = blockIdx.x * 4 + (threadIdx.x >> 6);
  int lane = threadIdx.x & 63;
  int h = gw & (NH - 1);
  int bt = gw / NH;               // 0..4095
  int t = bt & 2047, bb = bt >> 11;
  const u16* r = raw + (size_t)bt * stride + coloff + (size_t)h * 128;
  ushort2 own = *(const ushort2*)(r + 2 * lane);
  int pk = __shfl_xor(__builtin_bit_cast(int, own), 32);
  ushort2 par = __builtin_bit_cast(ushort2, pk);
  float x0 = bf2f(own.x), x1 = bf2f(own.y);
  float y0 = bf2f(par.x), y1 = bf2f(par.y);
  int f = (lane & 31) * 2;
  float2 c2 = *(const float2*)(ctab + t * 64 + f);
  float2 s2 = *(const float2*)(stab + t * 64 + f);
  bool hi = lane >= 32;
  float e0 = hi ? (x0 * c2.x + y0 * s2.x) : (x0 * c2.x - y0 * s2.x);
  float e1 = hi ? (x1 * c2.y + y1 * s2.y) : (x1 * c2.y - y1 * s2.y);
  float ss = e0 * e0 + e1 * e1;
#pragma unroll
  for (int off = 1; off < 64; off <<= 1) ss += __shfl_xor(ss, off);
  float inv = scale / (sqrtf(ss) + 1e-6f);
  float2 g2 = *(const float2*)(gamma + 2 * lane);
  size_t ob = (((size_t)(bb * NH + h)) * 2048 + t) * 128 + 2 * lane;
  ushort2 o = {f2bf(e0 * inv * g2.x), f2bf(e1 * inv * g2.y)};
  *(ushort2*)(out + ob) = o;
}

// ---------------- V transpose: qkv[B*T,3072] cols 2560.. -> [B, HK, 128, T] ----------------
__global__ __launch_bounds__(256) void transpose_v(const u16* __restrict__ qkv,
                                                   u16* __restrict__ vt) {
  __shared__ u16 tile[32][33];
  int t0 = blockIdx.x * 32, d0 = blockIdx.y * 32;
  int bh = blockIdx.z;
  int b = bh >> 2, hkk = bh & 3;
  int tx = threadIdx.x & 31, ty = threadIdx.x >> 5;  // ty 0..7
#pragma unroll
  for (int i = 0; i < 4; ++i) {
    int r = ty + i * 8;
    tile[r][tx] = qkv[((size_t)(b * 2048 + t0 + r)) * 3072 + 2560 + hkk * 128 + d0 + tx];
  }
  __syncthreads();
#pragma unroll
  for (int i = 0; i < 4; ++i) {
    int r = ty + i * 8;
    vt[((size_t)((b * 4 + hkk) * 128 + d0 + r)) * 2048 + t0 + tx] = tile[tx][r];
  }
}

// ---------------- flash attention (unchanged from R9) ----------------
__global__ __launch_bounds__(512, 4) void attn_kernel(const u16* __restrict__ Qr,
                                                      const u16* __restrict__ Kr,
                                                      const u16* __restrict__ Vt,
                                                      u16* __restrict__ Yt) {
  __shared__ u16 Ks[2][64 * 128];
  __shared__ u16 Vs[2][128 * 64];
  __shared__ u16 Ps[8][16 * 64];
  const int tid = threadIdx.x;
  const int lane = tid & 63;
  const int wv = tid >> 6;
  const int l16 = lane & 15, lhi = lane >> 4;
  const int work = (blockIdx.x & 7) * 64 + (blockIdx.x >> 3);
  const int q0b = (work & 15) << 7;
  const int bh = work >> 4;
  const int b = bh >> 4, h = bh & 15;
  const int hk = h >> 2;
  const int q0w = q0b + wv * 16;

  const u16* qbase = Qr + (((size_t)bh) * 2048 + q0w + l16) * 128;
  bf16x8 qf[4];
#pragma unroll
  for (int dc = 0; dc < 4; ++dc)
    qf[dc] = *(const bf16x8*)(qbase + dc * 32 + lhi * 8);

  const char* kg = (const char*)(Kr + ((size_t)(b * 4 + hk)) * 2048 * 128);
  const u16* vg = Vt + ((size_t)(b * 4 + hk)) * 2048 * 128;

  auto stage = [&](int buf, int s0) {
#pragma unroll
    for (int i = 0; i < 2; ++i) {
      int c = wv + 8 * i;
      int row = c * 4 + lhi;
      int srcb = (l16 * 16) ^ ((row & 7) << 4);
      gl_lds16(kg + (size_t)(s0 + row) * 256 + srcb, (char*)Ks[buf] + c * 1024);
    }
    int r8 = lane >> 3, c8 = lane & 7;
#pragma unroll
    for (int i = 0; i < 2; ++i) {
      int c = wv + 8 * i;
      int row = c * 8 + r8;
      int srcb = (c8 * 16) ^ ((r8 & 7) << 4);
      gl_lds16((const char*)(vg + (size_t)row * 2048 + s0) + srcb,
               (char*)Vs[buf] + c * 1024);
    }
  };

  const bf16x8 ones = {0x3F80, 0x3F80, 0x3F80, 0x3F80, 0x3F80, 0x3F80, 0x3F80, 0x3F80};
  float mbase = 0.f;
  f32x4 lacc = {};
  f32x4 oacc[8] = {};

  int s_lo = q0b - 1024; if (s_lo < 0) s_lo = 0;
  const int nt = (q0b + 128 - s_lo) >> 6;

  stage(0, s_lo);
  int cur = 0;
  for (int it = 0; it < nt; ++it) {
    const int s0 = s_lo + (it << 6);
    if (it + 1 < nt) {
      stage(cur ^ 1, s0 + 64);
      wait_vmcnt<4>();
    } else {
      wait_vmcnt<0>();
    }
    block_barrier();
    const bool skip = (q0w + 15 < s0) || (q0w - (s0 + 63) > 1024);
    if (!skip) {
      f32x4 sacc[4] = {};
      const char* ksb = (const char*)Ks[cur];
      __builtin_amdgcn_s_setprio(1);
#pragma unroll
      for (int n = 0; n < 4; ++n) {
        int row = n * 16 + l16;
#pragma unroll
        for (int dc = 0; dc < 4; ++dc) {
          bf16x8 kf = *(const bf16x8*)(ksb + row * 256 +
                                       ((dc * 64 + lhi * 16) ^ ((l16 & 7) << 4)));
          sacc[n] = MFMA(qf[dc], kf, sacc[n]);
        }
      }
      __builtin_amdgcn_s_setprio(0);
      const bool domask = (q0w < s0 + 63) || (q0w + 15 - s0 > 1024);
      if (domask) {
#pragma unroll
        for (int n = 0; n < 4; ++n)
#pragma unroll
          for (int j = 0; j < 4; ++j) {
            int q = q0w + lhi * 4 + j;
            int s = s0 + n * 16 + l16;
            if ((unsigned)(q - s) > 1024u) sacc[n][j] = -INFINITY;
          }
      }
      float mt = sacc[0][0];
#pragma unroll
      for (int n = 0; n < 4; ++n)
#pragma unroll
        for (int j = 0; j < 4; ++j) mt = fmaxf(mt, sacc[n][j]);
#pragma unroll
      for (int off = 1; off < 64; off <<= 1) mt = fmaxf(mt, __shfl_xor(mt, off));
      if (mt > mbase + 8.f) {
        float sc2 = exp2_hw(mbase - mt);
#pragma unroll
        for (int j = 0; j < 4; ++j) lacc[j] *= sc2;
#pragma unroll
        for (int dt = 0; dt < 8; ++dt)
#pragma unroll
          for (int j = 0; j < 4; ++j) oacc[dt][j] *= sc2;
        mbase = mt;
      }
      char* psb = (char*)Ps[wv];
#pragma unroll
      for (int n = 0; n < 4; ++n)
#pragma unroll
        for (int j = 0; j < 4; ++j) {
          float p = exp2_hw(sacc[n][j] - mbase);
          int R = lhi * 4 + j;
          *(u16*)(psb + R * 128 + (((n * 16 + l16) * 2) ^ ((R & 7) << 4))) = f2bf(p);
        }
      bf16x8 pf[2];
#pragma unroll
      for (int kk = 0; kk < 2; ++kk)
        pf[kk] = *(const bf16x8*)(psb + l16 * 128 +
                                  ((kk * 64 + lhi * 16) ^ ((l16 & 7) << 4)));
      const char* vsb = (const char*)Vs[cur];
      __builtin_amdgcn_s_setprio(1);
      lacc = MFMA(pf[0], ones, lacc);
      lacc = MFMA(pf[1], ones, lacc);
#pragma unroll
      for (int dt = 0; dt < 8; ++dt) {
        int row = dt * 16 + l16;
#pragma unroll
        for (int kk = 0; kk < 2; ++kk) {
          bf16x8 vf = *(const bf16x8*)(vsb + row * 128 +
                                       ((kk * 64 + lhi * 16) ^ ((l16 & 7) << 4)));
          oacc[dt] = MFMA(pf[kk], vf, oacc[dt]);
        }
      }
      __builtin_amdgcn_s_setprio(0);
    }
    block_barrier();
    cur ^= 1;
  }
#pragma unroll
  for (int j = 0; j < 4; ++j) {
    float inv = 1.0f / lacc[j];
    int q = q0w + lhi * 4 + j;
    size_t rowbase = ((size_t)(b * 2048 + q)) * 2048 + (size_t)h * 128;
#pragma unroll
    for (int dt = 0; dt < 8; ++dt)
      Yt[rowbase + dt * 16 + l16] = f2bf(oacc[dt][j] * inv);
  }
}

extern "C" void kernel_launch(void* const* d_in, const int* in_sizes, int n_in,
                              void* d_out, int out_size, void* d_ws, size_t ws_size,
                              hipStream_t stream) {
  (void)in_sizes; (void)n_in; (void)out_size; (void)ws_size;
  const float* x  = (const float*)d_in[0];
  const float* wq = (const float*)d_in[1];
  const float* wk = (const float*)d_in[2];
  const float* wv = (const float*)d_in[3];
  const float* wo = (const float*)d_in[4];
  const float* gq = (const float*)d_in[5];
  const float* gk = (const float*)d_in[6];
  float* out = (float*)d_out;
  char* ws = (char*)d_ws;

  size_t off = 0;
  auto alloc = [&](size_t bytes) {
    size_t o = off;
    off += (bytes + 255) & ~(size_t)255;
    return o;
  };
  u16* xb     = (u16*)(ws + alloc((size_t)4096 * 2048 * 2));
  u16* wqkvb  = (u16*)(ws + alloc((size_t)3072 * 2048 * 2));
  u16* wob    = (u16*)(ws + alloc((size_t)2048 * 2048 * 2));
  u16* qkvraw = (u16*)(ws + alloc((size_t)4096 * 3072 * 2));  // later reused as ytmp
  u16* qr     = (u16*)(ws + alloc((size_t)4096 * 2048 * 2));
  u16* kr     = (u16*)(ws + alloc((size_t)4096 * 512 * 2));
  u16* vt     = (u16*)(ws + alloc((size_t)4096 * 512 * 2));
  float* ctab = (float*)(ws + alloc((size_t)2048 * 64 * 4));
  float* stab = (float*)(ws + alloc((size_t)2048 * 64 * 4));
  u16* ytmp = qkvraw;  // safe: qkvraw fully consumed before attn writes

  const float sc_log2 = 0.12751744f;  // 1/sqrt(128) * log2(e)

  cvt_all<<<18432, 256, 0, stream>>>(x, wq, wk, wv, wo, xb, wqkvb, wob);
  rope_table<<<512, 256, 0, stream>>>(ctab, stab);

  // fused QKV projection: [4096,2048] x [3072,2048]^T -> [4096,3072]
  gemm_q<<<dim3(12, 16), 512, 0, stream>>>(xb, wqkvb, qkvraw, 4096, 3072, 2048);

  rope_norm<16><<<16384, 256, 0, stream>>>(qkvraw, qr, ctab, stab, gq, 3072, 0, sc_log2);
  rope_norm<4><<<4096, 256, 0, stream>>>(qkvraw, kr, ctab, stab, gk, 3072, 2048, 1.0f);
  transpose_v<<<dim3(64, 4, 8), 256, 0, stream>>>(qkvraw, vt);

  attn_kernel<<<dim3(512), 512, 0, stream>>>(qr, kr, vt, ytmp);

  // output projection (f32 out): 256x128 tiles -> 256 blocks (1/CU)
  gemm_o<<<dim3(16, 16), 512, 0, stream>>>(ytmp, wob, out, 4096, 2048, 2048);
}

// Round 12
// 202.344 us; speedup vs baseline: 1.7919x; 1.5375x over previous
//
#include <hip/hip_runtime.h>
#include <cstdint>
#include <cstddef>

typedef unsigned short u16;
typedef short bf16x8 __attribute__((ext_vector_type(8)));
typedef float f32x4 __attribute__((ext_vector_type(4)));

#define MFMA(a,b,c) __builtin_amdgcn_mfma_f32_16x16x32_bf16(a,b,c,0,0,0)

__device__ __forceinline__ u16 f2bf(float f) {
  unsigned u = __builtin_bit_cast(unsigned, f);
  u += 0x7fffu + ((u >> 16) & 1u);
  return (u16)(u >> 16);
}
__device__ __forceinline__ float bf2f(u16 b) {
  return __builtin_bit_cast(float, (unsigned)b << 16);
}
__device__ __forceinline__ float exp2_hw(float x) {
  float r;
  asm("v_exp_f32 %0, %1" : "=v"(r) : "v"(x));
  return r;
}
__device__ __forceinline__ void gl_lds16(const void* g, void* l) {
  __builtin_amdgcn_global_load_lds(
      (const __attribute__((address_space(1))) void*)g,
      (__attribute__((address_space(3))) void*)l, 16, 0, 0);
}
template <int N>
__device__ __forceinline__ void wait_vmcnt() {
  if constexpr (N == 0) asm volatile("s_waitcnt vmcnt(0)" ::: "memory");
  else if constexpr (N == 4) asm volatile("s_waitcnt vmcnt(4)" ::: "memory");
}
__device__ __forceinline__ void block_barrier() {
  __builtin_amdgcn_sched_barrier(0);
  __builtin_amdgcn_s_barrier();
  __builtin_amdgcn_sched_barrier(0);
}

// ---------------- fused f32 -> bf16 convert for all 5 inputs ----------------
__global__ __launch_bounds__(256) void cvt_all(const float* __restrict__ x,
                                               const float* __restrict__ wq,
                                               const float* __restrict__ wk,
                                               const float* __restrict__ wv,
                                               const float* __restrict__ wo,
                                               u16* __restrict__ xb,
                                               u16* __restrict__ wqkvb,
                                               u16* __restrict__ wob) {
  int idx = (blockIdx.x * 256 + threadIdx.x) * 4;
  const float* src;
  u16* dst;
  if (idx < 8388608) { src = x + idx; dst = xb + idx; }
  else if (idx < 12582912) { src = wq + (idx - 8388608); dst = wqkvb + (idx - 8388608); }
  else if (idx < 13631488) { src = wk + (idx - 12582912); dst = wqkvb + (idx - 8388608); }
  else if (idx < 14680064) { src = wv + (idx - 13631488); dst = wqkvb + (idx - 8388608); }
  else if (idx < 18874368) { src = wo + (idx - 14680064); dst = wob + (idx - 14680064); }
  else return;
  float4 v = *(const float4*)src;
  ushort4 o = {f2bf(v.x), f2bf(v.y), f2bf(v.z), f2bf(v.w)};
  *(ushort4*)dst = o;
}

// ---------------- RoPE cos/sin table: [T=2048][64] f32 ----------------
__global__ __launch_bounds__(256) void rope_table(float* __restrict__ ctab,
                                                  float* __restrict__ stab) {
  int i = blockIdx.x * 256 + threadIdx.x;  // 0 .. 131071
  int t = i >> 6, f = i & 63;
  float inv_freq = powf(10000.0f, -(2.0f * f) / 128.0f);
  float ang = (float)t * inv_freq;
  ctab[i] = cosf(ang);
  stab[i] = sinf(ang);
}

// ============ m97-style NT GEMM: 128x128 tile, BK=64, 4 waves, single LDS buffer ============
// 32KB LDS -> 3-4 blocks/CU co-resident (barrier drains overlap across blocks).
// Swizzled LDS (3-bit slot XOR) -> conflict-free ds_read_b128 fragment reads.
// acc[4][4] = 64 VGPR -> no spill risk.
template <int OUT_F32>
__global__ __launch_bounds__(256, 4) void gemm_m97(const u16* __restrict__ A,
                                                   const u16* __restrict__ Bw,
                                                   void* __restrict__ Cout,
                                                   int M, int N, int K) {
  __shared__ u16 As[128 * 64];   // 128 rows x 128B, swizzled
  __shared__ u16 Bs[128 * 64];
  const int tid = threadIdx.x;
  const int lane = tid & 63;
  const int wv = tid >> 6;           // 0..3
  const int l16 = lane & 15, lhi = lane >> 4;
  const int wm = wv >> 1, wn = wv & 1;   // 2x2 waves, each 64x64 output
  const int m0 = blockIdx.y * 128;
  const int n0 = blockIdx.x * 128;
  const int nt = K >> 6;

  const int srow8 = lane >> 3;                        // row within 8-row chunk
  const int scol = ((lane & 7) * 16) ^ (srow8 << 4);  // pre-swizzled source col byte

  f32x4 acc[4][4] = {};

  for (int t = 0; t < nt; ++t) {
    // stage: A,B each 16 chunks of 1KB (8 rows x 128B); wave does 4 of each
#pragma unroll
    for (int c = 0; c < 4; ++c) {
      int g = wv + 4 * c;
      int rowA = m0 + g * 8 + srow8;
      gl_lds16((const char*)A + ((size_t)rowA * K + (size_t)t * 64) * 2 + scol,
               (char*)As + g * 1024);
      int rowB = n0 + g * 8 + srow8;
      gl_lds16((const char*)Bw + ((size_t)rowB * K + (size_t)t * 64) * 2 + scol,
               (char*)Bs + g * 1024);
    }
    __syncthreads();
#pragma unroll
    for (int kk = 0; kk < 2; ++kk) {
      bf16x8 af[4], bfr[4];
#pragma unroll
      for (int mi = 0; mi < 4; ++mi) {
        int row = wm * 64 + mi * 16 + l16;
        af[mi] = *(const bf16x8*)((const char*)As + row * 128 +
                                  ((kk * 64 + lhi * 16) ^ ((l16 & 7) << 4)));
      }
#pragma unroll
      for (int ni = 0; ni < 4; ++ni) {
        int row = wn * 64 + ni * 16 + l16;
        bfr[ni] = *(const bf16x8*)((const char*)Bs + row * 128 +
                                   ((kk * 64 + lhi * 16) ^ ((l16 & 7) << 4)));
      }
      __builtin_amdgcn_s_setprio(1);
#pragma unroll
      for (int mi = 0; mi < 4; ++mi)
#pragma unroll
        for (int ni = 0; ni < 4; ++ni)
          acc[mi][ni] = MFMA(af[mi], bfr[ni], acc[mi][ni]);
      __builtin_amdgcn_s_setprio(0);
    }
    __syncthreads();
  }

  // epilogue
#pragma unroll
  for (int mi = 0; mi < 4; ++mi)
#pragma unroll
    for (int ni = 0; ni < 4; ++ni) {
      int col = n0 + wn * 64 + ni * 16 + l16;
#pragma unroll
      for (int j = 0; j < 4; ++j) {
        int row = m0 + wm * 64 + mi * 16 + lhi * 4 + j;
        float v = acc[mi][ni][j];
        if (OUT_F32)
          ((float*)Cout)[(size_t)row * N + col] = v;
        else
          ((u16*)Cout)[(size_t)row * N + col] = f2bf(v);
      }
    }
}

// ---------------- RoPE + L2 norm + gamma (vectorized: 4B/lane) ----------------
template <int NH>
__global__ __launch_bounds__(256) void rope_norm(const u16* __restrict__ raw,
                                                 u16* __restrict__ out,
                                                 const float* __restrict__ ctab,
                                                 const float* __restrict__ stab,
                                                 const float* __restrict__ gamma,
                                                 int stride, int coloff, float scale) {
  int gw = blockIdx.x * 4 + (threadIdx.x >> 6);
  int lane = threadIdx.x & 63;
  int h = gw & (NH - 1);
  int bt = gw / NH;               // 0..4095
  int t = bt & 2047, bb = bt >> 11;
  const u16* r = raw + (size_t)bt * stride + coloff + (size_t)h * 128;
  ushort2 own = *(const ushort2*)(r + 2 * lane);
  int pk = __shfl_xor(__builtin_bit_cast(int, own), 32);
  ushort2 par = __builtin_bit_cast(ushort2, pk);
  float x0 = bf2f(own.x), x1 = bf2f(own.y);
  float y0 = bf2f(par.x), y1 = bf2f(par.y);
  int f = (lane & 31) * 2;
  float2 c2 = *(const float2*)(ctab + t * 64 + f);
  float2 s2 = *(const float2*)(stab + t * 64 + f);
  bool hi = lane >= 32;
  float e0 = hi ? (x0 * c2.x + y0 * s2.x) : (x0 * c2.x - y0 * s2.x);
  float e1 = hi ? (x1 * c2.y + y1 * s2.y) : (x1 * c2.y - y1 * s2.y);
  float ss = e0 * e0 + e1 * e1;
#pragma unroll
  for (int off = 1; off < 64; off <<= 1) ss += __shfl_xor(ss, off);
  float inv = scale / (sqrtf(ss) + 1e-6f);
  float2 g2 = *(const float2*)(gamma + 2 * lane);
  size_t ob = (((size_t)(bb * NH + h)) * 2048 + t) * 128 + 2 * lane;
  ushort2 o = {f2bf(e0 * inv * g2.x), f2bf(e1 * inv * g2.y)};
  *(ushort2*)(out + ob) = o;
}

// ---------------- V transpose: qkv[B*T,3072] cols 2560.. -> [B, HK, 128, T] ----------------
__global__ __launch_bounds__(256) void transpose_v(const u16* __restrict__ qkv,
                                                   u16* __restrict__ vt) {
  __shared__ u16 tile[32][33];
  int t0 = blockIdx.x * 32, d0 = blockIdx.y * 32;
  int bh = blockIdx.z;
  int b = bh >> 2, hkk = bh & 3;
  int tx = threadIdx.x & 31, ty = threadIdx.x >> 5;  // ty 0..7
#pragma unroll
  for (int i = 0; i < 4; ++i) {
    int r = ty + i * 8;
    tile[r][tx] = qkv[((size_t)(b * 2048 + t0 + r)) * 3072 + 2560 + hkk * 128 + d0 + tx];
  }
  __syncthreads();
#pragma unroll
  for (int i = 0; i < 4; ++i) {
    int r = ty + i * 8;
    vt[((size_t)((b * 4 + hkk) * 128 + d0 + r)) * 2048 + t0 + tx] = tile[tx][r];
  }
}

// ---------------- flash attention (unchanged from R9) ----------------
__global__ __launch_bounds__(512, 4) void attn_kernel(const u16* __restrict__ Qr,
                                                      const u16* __restrict__ Kr,
                                                      const u16* __restrict__ Vt,
                                                      u16* __restrict__ Yt) {
  __shared__ u16 Ks[2][64 * 128];
  __shared__ u16 Vs[2][128 * 64];
  __shared__ u16 Ps[8][16 * 64];
  const int tid = threadIdx.x;
  const int lane = tid & 63;
  const int wv = tid >> 6;
  const int l16 = lane & 15, lhi = lane >> 4;
  const int work = (blockIdx.x & 7) * 64 + (blockIdx.x >> 3);
  const int q0b = (work & 15) << 7;
  const int bh = work >> 4;
  const int b = bh >> 4, h = bh & 15;
  const int hk = h >> 2;
  const int q0w = q0b + wv * 16;

  const u16* qbase = Qr + (((size_t)bh) * 2048 + q0w + l16) * 128;
  bf16x8 qf[4];
#pragma unroll
  for (int dc = 0; dc < 4; ++dc)
    qf[dc] = *(const bf16x8*)(qbase + dc * 32 + lhi * 8);

  const char* kg = (const char*)(Kr + ((size_t)(b * 4 + hk)) * 2048 * 128);
  const u16* vg = Vt + ((size_t)(b * 4 + hk)) * 2048 * 128;

  auto stage = [&](int buf, int s0) {
#pragma unroll
    for (int i = 0; i < 2; ++i) {
      int c = wv + 8 * i;
      int row = c * 4 + lhi;
      int srcb = (l16 * 16) ^ ((row & 7) << 4);
      gl_lds16(kg + (size_t)(s0 + row) * 256 + srcb, (char*)Ks[buf] + c * 1024);
    }
    int r8 = lane >> 3, c8 = lane & 7;
#pragma unroll
    for (int i = 0; i < 2; ++i) {
      int c = wv + 8 * i;
      int row = c * 8 + r8;
      int srcb = (c8 * 16) ^ ((r8 & 7) << 4);
      gl_lds16((const char*)(vg + (size_t)row * 2048 + s0) + srcb,
               (char*)Vs[buf] + c * 1024);
    }
  };

  const bf16x8 ones = {0x3F80, 0x3F80, 0x3F80, 0x3F80, 0x3F80, 0x3F80, 0x3F80, 0x3F80};
  float mbase = 0.f;
  f32x4 lacc = {};
  f32x4 oacc[8] = {};

  int s_lo = q0b - 1024; if (s_lo < 0) s_lo = 0;
  const int nt = (q0b + 128 - s_lo) >> 6;

  stage(0, s_lo);
  int cur = 0;
  for (int it = 0; it < nt; ++it) {
    const int s0 = s_lo + (it << 6);
    if (it + 1 < nt) {
      stage(cur ^ 1, s0 + 64);
      wait_vmcnt<4>();
    } else {
      wait_vmcnt<0>();
    }
    block_barrier();
    const bool skip = (q0w + 15 < s0) || (q0w - (s0 + 63) > 1024);
    if (!skip) {
      f32x4 sacc[4] = {};
      const char* ksb = (const char*)Ks[cur];
      __builtin_amdgcn_s_setprio(1);
#pragma unroll
      for (int n = 0; n < 4; ++n) {
        int row = n * 16 + l16;
#pragma unroll
        for (int dc = 0; dc < 4; ++dc) {
          bf16x8 kf = *(const bf16x8*)(ksb + row * 256 +
                                       ((dc * 64 + lhi * 16) ^ ((l16 & 7) << 4)));
          sacc[n] = MFMA(qf[dc], kf, sacc[n]);
        }
      }
      __builtin_amdgcn_s_setprio(0);
      const bool domask = (q0w < s0 + 63) || (q0w + 15 - s0 > 1024);
      if (domask) {
#pragma unroll
        for (int n = 0; n < 4; ++n)
#pragma unroll
          for (int j = 0; j < 4; ++j) {
            int q = q0w + lhi * 4 + j;
            int s = s0 + n * 16 + l16;
            if ((unsigned)(q - s) > 1024u) sacc[n][j] = -INFINITY;
          }
      }
      float mt = sacc[0][0];
#pragma unroll
      for (int n = 0; n < 4; ++n)
#pragma unroll
        for (int j = 0; j < 4; ++j) mt = fmaxf(mt, sacc[n][j]);
#pragma unroll
      for (int off = 1; off < 64; off <<= 1) mt = fmaxf(mt, __shfl_xor(mt, off));
      if (mt > mbase + 8.f) {
        float sc2 = exp2_hw(mbase - mt);
#pragma unroll
        for (int j = 0; j < 4; ++j) lacc[j] *= sc2;
#pragma unroll
        for (int dt = 0; dt < 8; ++dt)
#pragma unroll
          for (int j = 0; j < 4; ++j) oacc[dt][j] *= sc2;
        mbase = mt;
      }
      char* psb = (char*)Ps[wv];
#pragma unroll
      for (int n = 0; n < 4; ++n)
#pragma unroll
        for (int j = 0; j < 4; ++j) {
          float p = exp2_hw(sacc[n][j] - mbase);
          int R = lhi * 4 + j;
          *(u16*)(psb + R * 128 + (((n * 16 + l16) * 2) ^ ((R & 7) << 4))) = f2bf(p);
        }
      bf16x8 pf[2];
#pragma unroll
      for (int kk = 0; kk < 2; ++kk)
        pf[kk] = *(const bf16x8*)(psb + l16 * 128 +
                                  ((kk * 64 + lhi * 16) ^ ((l16 & 7) << 4)));
      const char* vsb = (const char*)Vs[cur];
      __builtin_amdgcn_s_setprio(1);
      lacc = MFMA(pf[0], ones, lacc);
      lacc = MFMA(pf[1], ones, lacc);
#pragma unroll
      for (int dt = 0; dt < 8; ++dt) {
        int row = dt * 16 + l16;
#pragma unroll
        for (int kk = 0; kk < 2; ++kk) {
          bf16x8 vf = *(const bf16x8*)(vsb + row * 128 +
                                       ((kk * 64 + lhi * 16) ^ ((l16 & 7) << 4)));
          oacc[dt] = MFMA(pf[kk], vf, oacc[dt]);
        }
      }
      __builtin_amdgcn_s_setprio(0);
    }
    block_barrier();
    cur ^= 1;
  }
#pragma unroll
  for (int j = 0; j < 4; ++j) {
    float inv = 1.0f / lacc[j];
    int q = q0w + lhi * 4 + j;
    size_t rowbase = ((size_t)(b * 2048 + q)) * 2048 + (size_t)h * 128;
#pragma unroll
    for (int dt = 0; dt < 8; ++dt)
      Yt[rowbase + dt * 16 + l16] = f2bf(oacc[dt][j] * inv);
  }
}

extern "C" void kernel_launch(void* const* d_in, const int* in_sizes, int n_in,
                              void* d_out, int out_size, void* d_ws, size_t ws_size,
                              hipStream_t stream) {
  (void)in_sizes; (void)n_in; (void)out_size; (void)ws_size;
  const float* x  = (const float*)d_in[0];
  const float* wq = (const float*)d_in[1];
  const float* wk = (const float*)d_in[2];
  const float* wv = (const float*)d_in[3];
  const float* wo = (const float*)d_in[4];
  const float* gq = (const float*)d_in[5];
  const float* gk = (const float*)d_in[6];
  float* out = (float*)d_out;
  char* ws = (char*)d_ws;

  size_t off = 0;
  auto alloc = [&](size_t bytes) {
    size_t o = off;
    off += (bytes + 255) & ~(size_t)255;
    return o;
  };
  u16* xb     = (u16*)(ws + alloc((size_t)4096 * 2048 * 2));
  u16* wqkvb  = (u16*)(ws + alloc((size_t)3072 * 2048 * 2));
  u16* wob    = (u16*)(ws + alloc((size_t)2048 * 2048 * 2));
  u16* qkvraw = (u16*)(ws + alloc((size_t)4096 * 3072 * 2));  // later reused as ytmp
  u16* qr     = (u16*)(ws + alloc((size_t)4096 * 2048 * 2));
  u16* kr     = (u16*)(ws + alloc((size_t)4096 * 512 * 2));
  u16* vt     = (u16*)(ws + alloc((size_t)4096 * 512 * 2));
  float* ctab = (float*)(ws + alloc((size_t)2048 * 64 * 4));
  float* stab = (float*)(ws + alloc((size_t)2048 * 64 * 4));
  u16* ytmp = qkvraw;  // safe: qkvraw fully consumed before attn writes

  const float sc_log2 = 0.12751744f;  // 1/sqrt(128) * log2(e)

  cvt_all<<<18432, 256, 0, stream>>>(x, wq, wk, wv, wo, xb, wqkvb, wob);
  rope_table<<<512, 256, 0, stream>>>(ctab, stab);

  // fused QKV projection: [4096,2048] x [3072,2048]^T -> [4096,3072]; 768 blocks (3/CU)
  gemm_m97<0><<<dim3(24, 32), 256, 0, stream>>>(xb, wqkvb, qkvraw, 4096, 3072, 2048);

  rope_norm<16><<<16384, 256, 0, stream>>>(qkvraw, qr, ctab, stab, gq, 3072, 0, sc_log2);
  rope_norm<4><<<4096, 256, 0, stream>>>(qkvraw, kr, ctab, stab, gk, 3072, 2048, 1.0f);
  transpose_v<<<dim3(64, 4, 8), 256, 0, stream>>>(qkvraw, vt);

  attn_kernel<<<dim3(512), 512, 0, stream>>>(qr, kr, vt, ytmp);

  // output projection (f32 out): 512 blocks (2/CU)
  gemm_m97<1><<<dim3(16, 32), 256, 0, stream>>>(ytmp, wob, out, 4096, 2048, 2048);
}

// Round 13
// 193.186 us; speedup vs baseline: 1.8769x; 1.0474x over previous
//
#include <hip/hip_runtime.h>
#include <cstdint>
#include <cstddef>

typedef unsigned short u16;
typedef short bf16x8 __attribute__((ext_vector_type(8)));
typedef float f32x4 __attribute__((ext_vector_type(4)));

#define MFMA(a,b,c) __builtin_amdgcn_mfma_f32_16x16x32_bf16(a,b,c,0,0,0)

__device__ __forceinline__ u16 f2bf(float f) {
  unsigned u = __builtin_bit_cast(unsigned, f);
  u += 0x7fffu + ((u >> 16) & 1u);
  return (u16)(u >> 16);
}
__device__ __forceinline__ float bf2f(u16 b) {
  return __builtin_bit_cast(float, (unsigned)b << 16);
}
__device__ __forceinline__ float exp2_hw(float x) {
  float r;
  asm("v_exp_f32 %0, %1" : "=v"(r) : "v"(x));
  return r;
}
__device__ __forceinline__ void gl_lds16(const void* g, void* l) {
  __builtin_amdgcn_global_load_lds(
      (const __attribute__((address_space(1))) void*)g,
      (__attribute__((address_space(3))) void*)l, 16, 0, 0);
}
template <int N>
__device__ __forceinline__ void wait_vmcnt() {
  if constexpr (N == 0) asm volatile("s_waitcnt vmcnt(0)" ::: "memory");
  else if constexpr (N == 4) asm volatile("s_waitcnt vmcnt(4)" ::: "memory");
}
__device__ __forceinline__ void block_barrier() {
  __builtin_amdgcn_sched_barrier(0);
  __builtin_amdgcn_s_barrier();
  __builtin_amdgcn_sched_barrier(0);
}

// ---------------- fused f32 -> bf16 convert for all 5 inputs ----------------
__global__ __launch_bounds__(256) void cvt_all(const float* __restrict__ x,
                                               const float* __restrict__ wq,
                                               const float* __restrict__ wk,
                                               const float* __restrict__ wv,
                                               const float* __restrict__ wo,
                                               u16* __restrict__ xb,
                                               u16* __restrict__ wqkvb,
                                               u16* __restrict__ wob) {
  int idx = (blockIdx.x * 256 + threadIdx.x) * 4;
  const float* src;
  u16* dst;
  if (idx < 8388608) { src = x + idx; dst = xb + idx; }
  else if (idx < 12582912) { src = wq + (idx - 8388608); dst = wqkvb + (idx - 8388608); }
  else if (idx < 13631488) { src = wk + (idx - 12582912); dst = wqkvb + (idx - 8388608); }
  else if (idx < 14680064) { src = wv + (idx - 13631488); dst = wqkvb + (idx - 8388608); }
  else if (idx < 18874368) { src = wo + (idx - 14680064); dst = wob + (idx - 14680064); }
  else return;
  float4 v = *(const float4*)src;
  ushort4 o = {f2bf(v.x), f2bf(v.y), f2bf(v.z), f2bf(v.w)};
  *(ushort4*)dst = o;
}

// ---------------- RoPE cos/sin table: [T=2048][64] f32 ----------------
__global__ __launch_bounds__(256) void rope_table(float* __restrict__ ctab,
                                                  float* __restrict__ stab) {
  int i = blockIdx.x * 256 + threadIdx.x;  // 0 .. 131071
  int t = i >> 6, f = i & 63;
  float inv_freq = powf(10000.0f, -(2.0f * f) / 128.0f);
  float ang = (float)t * inv_freq;
  ctab[i] = cosf(ang);
  stab[i] = sinf(ang);
}

// ============ m97-style NT GEMM: 128x128 tile, BK=64, 4 waves, single LDS buffer ============
template <int OUT_F32>
__global__ __launch_bounds__(256, 4) void gemm_m97(const u16* __restrict__ A,
                                                   const u16* __restrict__ Bw,
                                                   void* __restrict__ Cout,
                                                   int M, int N, int K) {
  __shared__ u16 As[128 * 64];   // 128 rows x 128B, swizzled
  __shared__ u16 Bs[128 * 64];
  const int tid = threadIdx.x;
  const int lane = tid & 63;
  const int wv = tid >> 6;           // 0..3
  const int l16 = lane & 15, lhi = lane >> 4;
  const int wm = wv >> 1, wn = wv & 1;   // 2x2 waves, each 64x64 output
  const int m0 = blockIdx.y * 128;
  const int n0 = blockIdx.x * 128;
  const int nt = K >> 6;

  const int srow8 = lane >> 3;                        // row within 8-row chunk
  const int scol = ((lane & 7) * 16) ^ (srow8 << 4);  // pre-swizzled source col byte

  f32x4 acc[4][4] = {};

  for (int t = 0; t < nt; ++t) {
#pragma unroll
    for (int c = 0; c < 4; ++c) {
      int g = wv + 4 * c;
      int rowA = m0 + g * 8 + srow8;
      gl_lds16((const char*)A + ((size_t)rowA * K + (size_t)t * 64) * 2 + scol,
               (char*)As + g * 1024);
      int rowB = n0 + g * 8 + srow8;
      gl_lds16((const char*)Bw + ((size_t)rowB * K + (size_t)t * 64) * 2 + scol,
               (char*)Bs + g * 1024);
    }
    __syncthreads();
#pragma unroll
    for (int kk = 0; kk < 2; ++kk) {
      bf16x8 af[4], bfr[4];
#pragma unroll
      for (int mi = 0; mi < 4; ++mi) {
        int row = wm * 64 + mi * 16 + l16;
        af[mi] = *(const bf16x8*)((const char*)As + row * 128 +
                                  ((kk * 64 + lhi * 16) ^ ((l16 & 7) << 4)));
      }
#pragma unroll
      for (int ni = 0; ni < 4; ++ni) {
        int row = wn * 64 + ni * 16 + l16;
        bfr[ni] = *(const bf16x8*)((const char*)Bs + row * 128 +
                                   ((kk * 64 + lhi * 16) ^ ((l16 & 7) << 4)));
      }
      __builtin_amdgcn_s_setprio(1);
#pragma unroll
      for (int mi = 0; mi < 4; ++mi)
#pragma unroll
        for (int ni = 0; ni < 4; ++ni)
          acc[mi][ni] = MFMA(af[mi], bfr[ni], acc[mi][ni]);
      __builtin_amdgcn_s_setprio(0);
    }
    __syncthreads();
  }

#pragma unroll
  for (int mi = 0; mi < 4; ++mi)
#pragma unroll
    for (int ni = 0; ni < 4; ++ni) {
      int col = n0 + wn * 64 + ni * 16 + l16;
#pragma unroll
      for (int j = 0; j < 4; ++j) {
        int row = m0 + wm * 64 + mi * 16 + lhi * 4 + j;
        float v = acc[mi][ni][j];
        if (OUT_F32)
          ((float*)Cout)[(size_t)row * N + col] = v;
        else
          ((u16*)Cout)[(size_t)row * N + col] = f2bf(v);
      }
    }
}

// ---------------- RoPE + L2 norm + gamma (vectorized: 4B/lane) ----------------
template <int NH>
__global__ __launch_bounds__(256) void rope_norm(const u16* __restrict__ raw,
                                                 u16* __restrict__ out,
                                                 const float* __restrict__ ctab,
                                                 const float* __restrict__ stab,
                                                 const float* __restrict__ gamma,
                                                 int stride, int coloff, float scale) {
  int gw = blockIdx.x * 4 + (threadIdx.x >> 6);
  int lane = threadIdx.x & 63;
  int h = gw & (NH - 1);
  int bt = gw / NH;               // 0..4095
  int t = bt & 2047, bb = bt >> 11;
  const u16* r = raw + (size_t)bt * stride + coloff + (size_t)h * 128;
  ushort2 own = *(const ushort2*)(r + 2 * lane);
  int pk = __shfl_xor(__builtin_bit_cast(int, own), 32);
  ushort2 par = __builtin_bit_cast(ushort2, pk);
  float x0 = bf2f(own.x), x1 = bf2f(own.y);
  float y0 = bf2f(par.x), y1 = bf2f(par.y);
  int f = (lane & 31) * 2;
  float2 c2 = *(const float2*)(ctab + t * 64 + f);
  float2 s2 = *(const float2*)(stab + t * 64 + f);
  bool hi = lane >= 32;
  float e0 = hi ? (x0 * c2.x + y0 * s2.x) : (x0 * c2.x - y0 * s2.x);
  float e1 = hi ? (x1 * c2.y + y1 * s2.y) : (x1 * c2.y - y1 * s2.y);
  float ss = e0 * e0 + e1 * e1;
#pragma unroll
  for (int off = 1; off < 64; off <<= 1) ss += __shfl_xor(ss, off);
  float inv = scale / (sqrtf(ss) + 1e-6f);
  float2 g2 = *(const float2*)(gamma + 2 * lane);
  size_t ob = (((size_t)(bb * NH + h)) * 2048 + t) * 128 + 2 * lane;
  ushort2 o = {f2bf(e0 * inv * g2.x), f2bf(e1 * inv * g2.y)};
  *(ushort2*)(out + ob) = o;
}

// ---------------- V transpose with sigma-permuted columns ----------------
// vt[d][block64*64 + c] = V[sigma(c)][d], sigma: c = l*2 + (n&1) + (n>>1)*32
// (kv = n*16 + l). Matches the packed-P k-slot order in attn (MFMA contracts
// k-slots by index, so identical permutation on P and V is exact).
__global__ __launch_bounds__(256) void transpose_v(const u16* __restrict__ qkv,
                                                   u16* __restrict__ vt) {
  __shared__ u16 tile[32][33];
  int t0 = blockIdx.x * 32, d0 = blockIdx.y * 32;
  int bh = blockIdx.z;
  int b = bh >> 2, hkk = bh & 3;
  int tx = threadIdx.x & 31, ty = threadIdx.x >> 5;  // ty 0..7
#pragma unroll
  for (int i = 0; i < 4; ++i) {
    int r = ty + i * 8;
    tile[r][tx] = qkv[((size_t)(b * 2048 + t0 + r)) * 3072 + 2560 + hkk * 128 + d0 + tx];
  }
  __syncthreads();
#pragma unroll
  for (int i = 0; i < 4; ++i) {
    int r = ty + i * 8;                 // d within 32
    int tg = t0 + tx;                   // actual kv position
    int n = (tg >> 4) & 3, l = tg & 15;
    int colp = (tg & ~63) + l * 2 + (n & 1) + ((n >> 1) << 5);
    vt[((size_t)((b * 4 + hkk) * 128 + d0 + r)) * 2048 + colp] = tile[tx][r];
  }
}

// ---------------- flash attention, sliding window 1024, QBLK=128, KVBLK=64 ----------------
// 8 waves, K+V double-buffered (swizzled LDS), counted-vmcnt gates, log2-domain
// softmax with wave-shared base + LAZY max (per-lane tree + __any trigger; the
// 6-shfl reduce only when the deferred-rescale actually fires), P stored in
// sigma-permuted order via packed b32 cvt_pk writes, rowsum via ones-MFMA.
__global__ __launch_bounds__(512, 4) void attn_kernel(const u16* __restrict__ Qr,
                                                      const u16* __restrict__ Kr,
                                                      const u16* __restrict__ Vt,
                                                      u16* __restrict__ Yt) {
  __shared__ u16 Ks[2][64 * 128];
  __shared__ u16 Vs[2][128 * 64];
  __shared__ u16 Ps[8][16 * 64];
  const int tid = threadIdx.x;
  const int lane = tid & 63;
  const int wv = tid >> 6;
  const int l16 = lane & 15, lhi = lane >> 4;
  const int work = (blockIdx.x & 7) * 64 + (blockIdx.x >> 3);
  const int q0b = (work & 15) << 7;
  const int bh = work >> 4;
  const int b = bh >> 4, h = bh & 15;
  const int hk = h >> 2;
  const int q0w = q0b + wv * 16;

  const u16* qbase = Qr + (((size_t)bh) * 2048 + q0w + l16) * 128;
  bf16x8 qf[4];
#pragma unroll
  for (int dc = 0; dc < 4; ++dc)
    qf[dc] = *(const bf16x8*)(qbase + dc * 32 + lhi * 8);

  const char* kg = (const char*)(Kr + ((size_t)(b * 4 + hk)) * 2048 * 128);
  const u16* vg = Vt + ((size_t)(b * 4 + hk)) * 2048 * 128;

  auto stage = [&](int buf, int s0) {
#pragma unroll
    for (int i = 0; i < 2; ++i) {
      int c = wv + 8 * i;
      int row = c * 4 + lhi;
      int srcb = (l16 * 16) ^ ((row & 7) << 4);
      gl_lds16(kg + (size_t)(s0 + row) * 256 + srcb, (char*)Ks[buf] + c * 1024);
    }
    int r8 = lane >> 3, c8 = lane & 7;
#pragma unroll
    for (int i = 0; i < 2; ++i) {
      int c = wv + 8 * i;
      int row = c * 8 + r8;
      int srcb = (c8 * 16) ^ ((r8 & 7) << 4);
      gl_lds16((const char*)(vg + (size_t)row * 2048 + s0) + srcb,
               (char*)Vs[buf] + c * 1024);
    }
  };

  const bf16x8 ones = {0x3F80, 0x3F80, 0x3F80, 0x3F80, 0x3F80, 0x3F80, 0x3F80, 0x3F80};
  float mbase = 0.f;
  f32x4 lacc = {};
  f32x4 oacc[8] = {};

  int s_lo = q0b - 1024; if (s_lo < 0) s_lo = 0;
  const int nt = (q0b + 128 - s_lo) >> 6;

  stage(0, s_lo);
  int cur = 0;
  for (int it = 0; it < nt; ++it) {
    const int s0 = s_lo + (it << 6);
    if (it + 1 < nt) {
      stage(cur ^ 1, s0 + 64);
      wait_vmcnt<4>();
    } else {
      wait_vmcnt<0>();
    }
    block_barrier();
    const bool skip = (q0w + 15 < s0) || (q0w - (s0 + 63) > 1024);
    if (!skip) {
      // QK^T (16 MFMA)
      f32x4 sacc[4] = {};
      const char* ksb = (const char*)Ks[cur];
      __builtin_amdgcn_s_setprio(1);
#pragma unroll
      for (int n = 0; n < 4; ++n) {
        int row = n * 16 + l16;
#pragma unroll
        for (int dc = 0; dc < 4; ++dc) {
          bf16x8 kf = *(const bf16x8*)(ksb + row * 256 +
                                       ((dc * 64 + lhi * 16) ^ ((l16 & 7) << 4)));
          sacc[n] = MFMA(qf[dc], kf, sacc[n]);
        }
      }
      __builtin_amdgcn_s_setprio(0);
      const bool domask = (q0w < s0 + 63) || (q0w + 15 - s0 > 1024);
      if (domask) {
#pragma unroll
        for (int n = 0; n < 4; ++n)
#pragma unroll
          for (int j = 0; j < 4; ++j) {
            int q = q0w + lhi * 4 + j;
            int s = s0 + n * 16 + l16;
            if ((unsigned)(q - s) > 1024u) sacc[n][j] = -INFINITY;
          }
      }
      // lazy max: per-lane tree + __any trigger (no DS shuffles steady-state)
      float nm[4];
#pragma unroll
      for (int n = 0; n < 4; ++n)
        nm[n] = fmaxf(fmaxf(sacc[n][0], sacc[n][1]), fmaxf(sacc[n][2], sacc[n][3]));
      float lm = fmaxf(fmaxf(nm[0], nm[1]), fmaxf(nm[2], nm[3]));
      if (__any(lm > mbase + 8.f)) {
        float mt = lm;
#pragma unroll
        for (int off = 1; off < 64; off <<= 1) mt = fmaxf(mt, __shfl_xor(mt, off));
        float sc2 = exp2_hw(mbase - mt);
#pragma unroll
        for (int j = 0; j < 4; ++j) lacc[j] *= sc2;
#pragma unroll
        for (int dt = 0; dt < 8; ++dt)
#pragma unroll
          for (int j = 0; j < 4; ++j) oacc[dt][j] *= sc2;
        mbase = mt;
      }
      // P = 2^(s - base): sigma-permuted storage, packed b32 cvt_pk writes.
      // storage elem c = l16*2 + (n&1) + (n>>1)*32  (kv = n*16 + l16)
      char* psb = (char*)Ps[wv];
#pragma unroll
      for (int j = 0; j < 4; ++j) {
        int R = lhi * 4 + j;
        float p0 = exp2_hw(sacc[0][j] - mbase);
        float p1 = exp2_hw(sacc[1][j] - mbase);
        float p2 = exp2_hw(sacc[2][j] - mbase);
        float p3 = exp2_hw(sacc[3][j] - mbase);
        unsigned r01, r23;
        asm("v_cvt_pk_bf16_f32 %0, %1, %2" : "=v"(r01) : "v"(p0), "v"(p1));
        asm("v_cvt_pk_bf16_f32 %0, %1, %2" : "=v"(r23) : "v"(p2), "v"(p3));
        *(unsigned*)(psb + R * 128 + ((l16 * 4) ^ ((R & 7) << 4))) = r01;
        *(unsigned*)(psb + R * 128 + ((64 + l16 * 4) ^ ((R & 7) << 4))) = r23;
      }
      // PV + rowsum (18 MFMA); V content is sigma-permuted to match
      bf16x8 pf[2];
#pragma unroll
      for (int kk = 0; kk < 2; ++kk)
        pf[kk] = *(const bf16x8*)(psb + l16 * 128 +
                                  ((kk * 64 + lhi * 16) ^ ((l16 & 7) << 4)));
      const char* vsb = (const char*)Vs[cur];
      __builtin_amdgcn_s_setprio(1);
      lacc = MFMA(pf[0], ones, lacc);
      lacc = MFMA(pf[1], ones, lacc);
#pragma unroll
      for (int dt = 0; dt < 8; ++dt) {
        int row = dt * 16 + l16;
#pragma unroll
        for (int kk = 0; kk < 2; ++kk) {
          bf16x8 vf = *(const bf16x8*)(vsb + row * 128 +
                                       ((kk * 64 + lhi * 16) ^ ((l16 & 7) << 4)));
          oacc[dt] = MFMA(pf[kk], vf, oacc[dt]);
        }
      }
      __builtin_amdgcn_s_setprio(0);
    }
    block_barrier();
    cur ^= 1;
  }
#pragma unroll
  for (int j = 0; j < 4; ++j) {
    float inv = 1.0f / lacc[j];
    int q = q0w + lhi * 4 + j;
    size_t rowbase = ((size_t)(b * 2048 + q)) * 2048 + (size_t)h * 128;
#pragma unroll
    for (int dt = 0; dt < 8; ++dt)
      Yt[rowbase + dt * 16 + l16] = f2bf(oacc[dt][j] * inv);
  }
}

extern "C" void kernel_launch(void* const* d_in, const int* in_sizes, int n_in,
                              void* d_out, int out_size, void* d_ws, size_t ws_size,
                              hipStream_t stream) {
  (void)in_sizes; (void)n_in; (void)out_size; (void)ws_size;
  const float* x  = (const float*)d_in[0];
  const float* wq = (const float*)d_in[1];
  const float* wk = (const float*)d_in[2];
  const float* wv = (const float*)d_in[3];
  const float* wo = (const float*)d_in[4];
  const float* gq = (const float*)d_in[5];
  const float* gk = (const float*)d_in[6];
  float* out = (float*)d_out;
  char* ws = (char*)d_ws;

  size_t off = 0;
  auto alloc = [&](size_t bytes) {
    size_t o = off;
    off += (bytes + 255) & ~(size_t)255;
    return o;
  };
  u16* xb     = (u16*)(ws + alloc((size_t)4096 * 2048 * 2));
  u16* wqkvb  = (u16*)(ws + alloc((size_t)3072 * 2048 * 2));
  u16* wob    = (u16*)(ws + alloc((size_t)2048 * 2048 * 2));
  u16* qkvraw = (u16*)(ws + alloc((size_t)4096 * 3072 * 2));  // later reused as ytmp
  u16* qr     = (u16*)(ws + alloc((size_t)4096 * 2048 * 2));
  u16* kr     = (u16*)(ws + alloc((size_t)4096 * 512 * 2));
  u16* vt     = (u16*)(ws + alloc((size_t)4096 * 512 * 2));
  float* ctab = (float*)(ws + alloc((size_t)2048 * 64 * 4));
  float* stab = (float*)(ws + alloc((size_t)2048 * 64 * 4));
  u16* ytmp = qkvraw;  // safe: qkvraw fully consumed before attn writes

  const float sc_log2 = 0.12751744f;  // 1/sqrt(128) * log2(e)

  cvt_all<<<18432, 256, 0, stream>>>(x, wq, wk, wv, wo, xb, wqkvb, wob);
  rope_table<<<512, 256, 0, stream>>>(ctab, stab);

  // fused QKV projection: [4096,2048] x [3072,2048]^T -> [4096,3072]; 768 blocks (3/CU)
  gemm_m97<0><<<dim3(24, 32), 256, 0, stream>>>(xb, wqkvb, qkvraw, 4096, 3072, 2048);

  rope_norm<16><<<16384, 256, 0, stream>>>(qkvraw, qr, ctab, stab, gq, 3072, 0, sc_log2);
  rope_norm<4><<<4096, 256, 0, stream>>>(qkvraw, kr, ctab, stab, gk, 3072, 2048, 1.0f);
  transpose_v<<<dim3(64, 4, 8), 256, 0, stream>>>(qkvraw, vt);

  attn_kernel<<<dim3(512), 512, 0, stream>>>(qr, kr, vt, ytmp);

  // output projection (f32 out): 512 blocks (2/CU)
  gemm_m97<1><<<dim3(16, 32), 256, 0, stream>>>(ytmp, wob, out, 4096, 2048, 2048);
}

// Round 14
// 191.595 us; speedup vs baseline: 1.8925x; 1.0083x over previous
//
#include <hip/hip_runtime.h>
#include <cstdint>
#include <cstddef>

typedef unsigned short u16;
typedef short bf16x8 __attribute__((ext_vector_type(8)));
typedef float f32x4 __attribute__((ext_vector_type(4)));

#define MFMA(a,b,c) __builtin_amdgcn_mfma_f32_16x16x32_bf16(a,b,c,0,0,0)

__device__ __forceinline__ u16 f2bf(float f) {
  unsigned u = __builtin_bit_cast(unsigned, f);
  u += 0x7fffu + ((u >> 16) & 1u);
  return (u16)(u >> 16);
}
__device__ __forceinline__ float bf2f(u16 b) {
  return __builtin_bit_cast(float, (unsigned)b << 16);
}
__device__ __forceinline__ float exp2_hw(float x) {
  float r;
  asm("v_exp_f32 %0, %1" : "=v"(r) : "v"(x));
  return r;
}
__device__ __forceinline__ void gl_lds16(const void* g, void* l) {
  __builtin_amdgcn_global_load_lds(
      (const __attribute__((address_space(1))) void*)g,
      (__attribute__((address_space(3))) void*)l, 16, 0, 0);
}
template <int N>
__device__ __forceinline__ void wait_vmcnt() {
  if constexpr (N == 0) asm volatile("s_waitcnt vmcnt(0)" ::: "memory");
  else if constexpr (N == 4) asm volatile("s_waitcnt vmcnt(4)" ::: "memory");
  else if constexpr (N == 8) asm volatile("s_waitcnt vmcnt(8)" ::: "memory");
}
__device__ __forceinline__ void lgkm0_fence() {
  asm volatile("s_waitcnt lgkmcnt(0)" ::: "memory");
  __builtin_amdgcn_sched_barrier(0);
}
__device__ __forceinline__ void block_barrier() {
  __builtin_amdgcn_sched_barrier(0);
  __builtin_amdgcn_s_barrier();
  __builtin_amdgcn_sched_barrier(0);
}

// ---------------- fused f32 -> bf16 convert for all 5 inputs ----------------
__global__ __launch_bounds__(256) void cvt_all(const float* __restrict__ x,
                                               const float* __restrict__ wq,
                                               const float* __restrict__ wk,
                                               const float* __restrict__ wv,
                                               const float* __restrict__ wo,
                                               u16* __restrict__ xb,
                                               u16* __restrict__ wqkvb,
                                               u16* __restrict__ wob) {
  int idx = (blockIdx.x * 256 + threadIdx.x) * 4;
  const float* src;
  u16* dst;
  if (idx < 8388608) { src = x + idx; dst = xb + idx; }
  else if (idx < 12582912) { src = wq + (idx - 8388608); dst = wqkvb + (idx - 8388608); }
  else if (idx < 13631488) { src = wk + (idx - 12582912); dst = wqkvb + (idx - 8388608); }
  else if (idx < 14680064) { src = wv + (idx - 13631488); dst = wqkvb + (idx - 8388608); }
  else if (idx < 18874368) { src = wo + (idx - 14680064); dst = wob + (idx - 14680064); }
  else return;
  float4 v = *(const float4*)src;
  ushort4 o = {f2bf(v.x), f2bf(v.y), f2bf(v.z), f2bf(v.w)};
  *(ushort4*)dst = o;
}

// ---------------- RoPE cos/sin table: [T=2048][64] f32 ----------------
__global__ __launch_bounds__(256) void rope_table(float* __restrict__ ctab,
                                                  float* __restrict__ stab) {
  int i = blockIdx.x * 256 + threadIdx.x;  // 0 .. 131071
  int t = i >> 6, f = i & 63;
  float inv_freq = powf(10000.0f, -(2.0f * f) / 128.0f);
  float ang = (float)t * inv_freq;
  ctab[i] = cosf(ang);
  stab[i] = sinf(ang);
}

// ============ 2-phase counted-vmcnt NT GEMM: 128x128 tile, BK=64, 4 waves ============
// R8's proven 2-buffer ledger on m97's geometry. 64KB LDS -> 2 blocks/CU, full grid
// fill. Per tile: {8 ds_read kk0; lgkm0; 16 MFMA} {8 ds_read kk1; lgkm0; barrier;
// stage(t+2 -> buf b); 16 MFMA; vmcnt(8); barrier}. Mid-loop never drains to 0.
template <int OUT_F32>
__global__ __launch_bounds__(256, 2) void gemm_2ph(const u16* __restrict__ A,
                                                   const u16* __restrict__ Bw,
                                                   void* __restrict__ Cout,
                                                   int M, int N, int K) {
  __shared__ u16 As[2][128 * 64];   // 128 rows x 128B, swizzled
  __shared__ u16 Bs[2][128 * 64];
  const int tid = threadIdx.x;
  const int lane = tid & 63;
  const int wv = tid >> 6;           // 0..3
  const int l16 = lane & 15, lhi = lane >> 4;
  const int wm = wv >> 1, wn = wv & 1;   // 2x2 waves, each 64x64 output
  const int m0 = blockIdx.y * 128;
  const int n0 = blockIdx.x * 128;
  const int nt = K >> 6;

  const int srow8 = lane >> 3;
  const int scol = ((lane & 7) * 16) ^ (srow8 << 4);  // pre-swizzled source col byte

  auto stage = [&](int buf, int kt) {   // 8 gl_lds per wave (4 A + 4 B chunks)
#pragma unroll
    for (int c = 0; c < 4; ++c) {
      int g = wv + 4 * c;
      int rowA = m0 + g * 8 + srow8;
      gl_lds16((const char*)A + ((size_t)rowA * K + (size_t)kt * 64) * 2 + scol,
               (char*)As[buf] + g * 1024);
      int rowB = n0 + g * 8 + srow8;
      gl_lds16((const char*)Bw + ((size_t)rowB * K + (size_t)kt * 64) * 2 + scol,
               (char*)Bs[buf] + g * 1024);
    }
  };
  auto rdA = [&](int buf, int mi, int kk) -> bf16x8 {
    int row = wm * 64 + mi * 16 + l16;
    return *(const bf16x8*)((const char*)As[buf] + row * 128 +
                            ((kk * 64 + lhi * 16) ^ ((l16 & 7) << 4)));
  };
  auto rdB = [&](int buf, int ni, int kk) -> bf16x8 {
    int row = wn * 64 + ni * 16 + l16;
    return *(const bf16x8*)((const char*)Bs[buf] + row * 128 +
                            ((kk * 64 + lhi * 16) ^ ((l16 & 7) << 4)));
  };

  f32x4 acc[4][4] = {};

  // prologue: stage tiles 0 and 1; retire tile0 (tile1's 8 stay in flight)
  stage(0, 0);
  stage(1, 1);
  wait_vmcnt<8>();
  block_barrier();

  for (int t = 0; t < nt; ++t) {
    const int b = t & 1;
    // ---- PH0: kk0 ----
    {
      bf16x8 af[4], bfr[4];
#pragma unroll
      for (int ni = 0; ni < 4; ++ni) bfr[ni] = rdB(b, ni, 0);
#pragma unroll
      for (int mi = 0; mi < 4; ++mi) af[mi] = rdA(b, mi, 0);
      lgkm0_fence();
      __builtin_amdgcn_s_setprio(1);
#pragma unroll
      for (int mi = 0; mi < 4; ++mi)
#pragma unroll
        for (int ni = 0; ni < 4; ++ni)
          acc[mi][ni] = MFMA(af[mi], bfr[ni], acc[mi][ni]);
      __builtin_amdgcn_s_setprio(0);
    }
    // ---- PH1: kk1 + stage + counted gate ----
    {
      bf16x8 af[4], bfr[4];
#pragma unroll
      for (int ni = 0; ni < 4; ++ni) bfr[ni] = rdB(b, ni, 1);
#pragma unroll
      for (int mi = 0; mi < 4; ++mi) af[mi] = rdA(b, mi, 1);
      lgkm0_fence();                 // all buf-b reads in regs
      block_barrier();               // all waves done reading buf b
      if (t + 2 < nt) stage(b, t + 2);   // safe overwrite of freed buffer
      __builtin_amdgcn_s_setprio(1);
#pragma unroll
      for (int mi = 0; mi < 4; ++mi)
#pragma unroll
        for (int ni = 0; ni < 4; ++ni)
          acc[mi][ni] = MFMA(af[mi], bfr[ni], acc[mi][ni]);
      __builtin_amdgcn_s_setprio(0);
      if (t + 2 < nt) wait_vmcnt<8>();      // retire t+1's 8; t+2's stay in flight
      else if (t + 1 < nt) wait_vmcnt<0>(); // tail
      block_barrier();
    }
  }

  // epilogue
#pragma unroll
  for (int mi = 0; mi < 4; ++mi)
#pragma unroll
    for (int ni = 0; ni < 4; ++ni) {
      int col = n0 + wn * 64 + ni * 16 + l16;
#pragma unroll
      for (int j = 0; j < 4; ++j) {
        int row = m0 + wm * 64 + mi * 16 + lhi * 4 + j;
        float v = acc[mi][ni][j];
        if (OUT_F32)
          ((float*)Cout)[(size_t)row * N + col] = v;
        else
          ((u16*)Cout)[(size_t)row * N + col] = f2bf(v);
      }
    }
}

// ---------------- RoPE + L2 norm + gamma (vectorized: 4B/lane) ----------------
template <int NH>
__global__ __launch_bounds__(256) void rope_norm(const u16* __restrict__ raw,
                                                 u16* __restrict__ out,
                                                 const float* __restrict__ ctab,
                                                 const float* __restrict__ stab,
                                                 const float* __restrict__ gamma,
                                                 int stride, int coloff, float scale) {
  int gw = blockIdx.x * 4 + (threadIdx.x >> 6);
  int lane = threadIdx.x & 63;
  int h = gw & (NH - 1);
  int bt = gw / NH;               // 0..4095
  int t = bt & 2047, bb = bt >> 11;
  const u16* r = raw + (size_t)bt * stride + coloff + (size_t)h * 128;
  ushort2 own = *(const ushort2*)(r + 2 * lane);
  int pk = __shfl_xor(__builtin_bit_cast(int, own), 32);
  ushort2 par = __builtin_bit_cast(ushort2, pk);
  float x0 = bf2f(own.x), x1 = bf2f(own.y);
  float y0 = bf2f(par.x), y1 = bf2f(par.y);
  int f = (lane & 31) * 2;
  float2 c2 = *(const float2*)(ctab + t * 64 + f);
  float2 s2 = *(const float2*)(stab + t * 64 + f);
  bool hi = lane >= 32;
  float e0 = hi ? (x0 * c2.x + y0 * s2.x) : (x0 * c2.x - y0 * s2.x);
  float e1 = hi ? (x1 * c2.y + y1 * s2.y) : (x1 * c2.y - y1 * s2.y);
  float ss = e0 * e0 + e1 * e1;
#pragma unroll
  for (int off = 1; off < 64; off <<= 1) ss += __shfl_xor(ss, off);
  float inv = scale / (sqrtf(ss) + 1e-6f);
  float2 g2 = *(const float2*)(gamma + 2 * lane);
  size_t ob = (((size_t)(bb * NH + h)) * 2048 + t) * 128 + 2 * lane;
  ushort2 o = {f2bf(e0 * inv * g2.x), f2bf(e1 * inv * g2.y)};
  *(ushort2*)(out + ob) = o;
}

// ---------------- V transpose with sigma-permuted columns ----------------
// vt[d][block64*64 + c] = V[sigma(c)][d], sigma: c = l*2 + (n&1) + (n>>1)*32
// (kv = n*16 + l). Matches the packed-P k-slot order in attn.
__global__ __launch_bounds__(256) void transpose_v(const u16* __restrict__ qkv,
                                                   u16* __restrict__ vt) {
  __shared__ u16 tile[32][33];
  int t0 = blockIdx.x * 32, d0 = blockIdx.y * 32;
  int bh = blockIdx.z;
  int b = bh >> 2, hkk = bh & 3;
  int tx = threadIdx.x & 31, ty = threadIdx.x >> 5;  // ty 0..7
#pragma unroll
  for (int i = 0; i < 4; ++i) {
    int r = ty + i * 8;
    tile[r][tx] = qkv[((size_t)(b * 2048 + t0 + r)) * 3072 + 2560 + hkk * 128 + d0 + tx];
  }
  __syncthreads();
#pragma unroll
  for (int i = 0; i < 4; ++i) {
    int r = ty + i * 8;                 // d within 32
    int tg = t0 + tx;                   // actual kv position
    int n = (tg >> 4) & 3, l = tg & 15;
    int colp = (tg & ~63) + l * 2 + (n & 1) + ((n >> 1) << 5);
    vt[((size_t)((b * 4 + hkk) * 128 + d0 + r)) * 2048 + colp] = tile[tx][r];
  }
}

// ---------------- flash attention (unchanged from R13) ----------------
__global__ __launch_bounds__(512, 4) void attn_kernel(const u16* __restrict__ Qr,
                                                      const u16* __restrict__ Kr,
                                                      const u16* __restrict__ Vt,
                                                      u16* __restrict__ Yt) {
  __shared__ u16 Ks[2][64 * 128];
  __shared__ u16 Vs[2][128 * 64];
  __shared__ u16 Ps[8][16 * 64];
  const int tid = threadIdx.x;
  const int lane = tid & 63;
  const int wv = tid >> 6;
  const int l16 = lane & 15, lhi = lane >> 4;
  const int work = (blockIdx.x & 7) * 64 + (blockIdx.x >> 3);
  const int q0b = (work & 15) << 7;
  const int bh = work >> 4;
  const int b = bh >> 4, h = bh & 15;
  const int hk = h >> 2;
  const int q0w = q0b + wv * 16;

  const u16* qbase = Qr + (((size_t)bh) * 2048 + q0w + l16) * 128;
  bf16x8 qf[4];
#pragma unroll
  for (int dc = 0; dc < 4; ++dc)
    qf[dc] = *(const bf16x8*)(qbase + dc * 32 + lhi * 8);

  const char* kg = (const char*)(Kr + ((size_t)(b * 4 + hk)) * 2048 * 128);
  const u16* vg = Vt + ((size_t)(b * 4 + hk)) * 2048 * 128;

  auto stage = [&](int buf, int s0) {
#pragma unroll
    for (int i = 0; i < 2; ++i) {
      int c = wv + 8 * i;
      int row = c * 4 + lhi;
      int srcb = (l16 * 16) ^ ((row & 7) << 4);
      gl_lds16(kg + (size_t)(s0 + row) * 256 + srcb, (char*)Ks[buf] + c * 1024);
    }
    int r8 = lane >> 3, c8 = lane & 7;
#pragma unroll
    for (int i = 0; i < 2; ++i) {
      int c = wv + 8 * i;
      int row = c * 8 + r8;
      int srcb = (c8 * 16) ^ ((r8 & 7) << 4);
      gl_lds16((const char*)(vg + (size_t)row * 2048 + s0) + srcb,
               (char*)Vs[buf] + c * 1024);
    }
  };

  const bf16x8 ones = {0x3F80, 0x3F80, 0x3F80, 0x3F80, 0x3F80, 0x3F80, 0x3F80, 0x3F80};
  float mbase = 0.f;
  f32x4 lacc = {};
  f32x4 oacc[8] = {};

  int s_lo = q0b - 1024; if (s_lo < 0) s_lo = 0;
  const int nt = (q0b + 128 - s_lo) >> 6;

  stage(0, s_lo);
  int cur = 0;
  for (int it = 0; it < nt; ++it) {
    const int s0 = s_lo + (it << 6);
    if (it + 1 < nt) {
      stage(cur ^ 1, s0 + 64);
      wait_vmcnt<4>();
    } else {
      wait_vmcnt<0>();
    }
    block_barrier();
    const bool skip = (q0w + 15 < s0) || (q0w - (s0 + 63) > 1024);
    if (!skip) {
      f32x4 sacc[4] = {};
      const char* ksb = (const char*)Ks[cur];
      __builtin_amdgcn_s_setprio(1);
#pragma unroll
      for (int n = 0; n < 4; ++n) {
        int row = n * 16 + l16;
#pragma unroll
        for (int dc = 0; dc < 4; ++dc) {
          bf16x8 kf = *(const bf16x8*)(ksb + row * 256 +
                                       ((dc * 64 + lhi * 16) ^ ((l16 & 7) << 4)));
          sacc[n] = MFMA(qf[dc], kf, sacc[n]);
        }
      }
      __builtin_amdgcn_s_setprio(0);
      const bool domask = (q0w < s0 + 63) || (q0w + 15 - s0 > 1024);
      if (domask) {
#pragma unroll
        for (int n = 0; n < 4; ++n)
#pragma unroll
          for (int j = 0; j < 4; ++j) {
            int q = q0w + lhi * 4 + j;
            int s = s0 + n * 16 + l16;
            if ((unsigned)(q - s) > 1024u) sacc[n][j] = -INFINITY;
          }
      }
      float nm[4];
#pragma unroll
      for (int n = 0; n < 4; ++n)
        nm[n] = fmaxf(fmaxf(sacc[n][0], sacc[n][1]), fmaxf(sacc[n][2], sacc[n][3]));
      float lm = fmaxf(fmaxf(nm[0], nm[1]), fmaxf(nm[2], nm[3]));
      if (__any(lm > mbase + 8.f)) {
        float mt = lm;
#pragma unroll
        for (int off = 1; off < 64; off <<= 1) mt = fmaxf(mt, __shfl_xor(mt, off));
        float sc2 = exp2_hw(mbase - mt);
#pragma unroll
        for (int j = 0; j < 4; ++j) lacc[j] *= sc2;
#pragma unroll
        for (int dt = 0; dt < 8; ++dt)
#pragma unroll
          for (int j = 0; j < 4; ++j) oacc[dt][j] *= sc2;
        mbase = mt;
      }
      char* psb = (char*)Ps[wv];
#pragma unroll
      for (int j = 0; j < 4; ++j) {
        int R = lhi * 4 + j;
        float p0 = exp2_hw(sacc[0][j] - mbase);
        float p1 = exp2_hw(sacc[1][j] - mbase);
        float p2 = exp2_hw(sacc[2][j] - mbase);
        float p3 = exp2_hw(sacc[3][j] - mbase);
        unsigned r01, r23;
        asm("v_cvt_pk_bf16_f32 %0, %1, %2" : "=v"(r01) : "v"(p0), "v"(p1));
        asm("v_cvt_pk_bf16_f32 %0, %1, %2" : "=v"(r23) : "v"(p2), "v"(p3));
        *(unsigned*)(psb + R * 128 + ((l16 * 4) ^ ((R & 7) << 4))) = r01;
        *(unsigned*)(psb + R * 128 + ((64 + l16 * 4) ^ ((R & 7) << 4))) = r23;
      }
      bf16x8 pf[2];
#pragma unroll
      for (int kk = 0; kk < 2; ++kk)
        pf[kk] = *(const bf16x8*)(psb + l16 * 128 +
                                  ((kk * 64 + lhi * 16) ^ ((l16 & 7) << 4)));
      const char* vsb = (const char*)Vs[cur];
      __builtin_amdgcn_s_setprio(1);
      lacc = MFMA(pf[0], ones, lacc);
      lacc = MFMA(pf[1], ones, lacc);
#pragma unroll
      for (int dt = 0; dt < 8; ++dt) {
        int row = dt * 16 + l16;
#pragma unroll
        for (int kk = 0; kk < 2; ++kk) {
          bf16x8 vf = *(const bf16x8*)(vsb + row * 128 +
                                       ((kk * 64 + lhi * 16) ^ ((l16 & 7) << 4)));
          oacc[dt] = MFMA(pf[kk], vf, oacc[dt]);
        }
      }
      __builtin_amdgcn_s_setprio(0);
    }
    block_barrier();
    cur ^= 1;
  }
#pragma unroll
  for (int j = 0; j < 4; ++j) {
    float inv = 1.0f / lacc[j];
    int q = q0w + lhi * 4 + j;
    size_t rowbase = ((size_t)(b * 2048 + q)) * 2048 + (size_t)h * 128;
#pragma unroll
    for (int dt = 0; dt < 8; ++dt)
      Yt[rowbase + dt * 16 + l16] = f2bf(oacc[dt][j] * inv);
  }
}

extern "C" void kernel_launch(void* const* d_in, const int* in_sizes, int n_in,
                              void* d_out, int out_size, void* d_ws, size_t ws_size,
                              hipStream_t stream) {
  (void)in_sizes; (void)n_in; (void)out_size; (void)ws_size;
  const float* x  = (const float*)d_in[0];
  const float* wq = (const float*)d_in[1];
  const float* wk = (const float*)d_in[2];
  const float* wv = (const float*)d_in[3];
  const float* wo = (const float*)d_in[4];
  const float* gq = (const float*)d_in[5];
  const float* gk = (const float*)d_in[6];
  float* out = (float*)d_out;
  char* ws = (char*)d_ws;

  size_t off = 0;
  auto alloc = [&](size_t bytes) {
    size_t o = off;
    off += (bytes + 255) & ~(size_t)255;
    return o;
  };
  u16* xb     = (u16*)(ws + alloc((size_t)4096 * 2048 * 2));
  u16* wqkvb  = (u16*)(ws + alloc((size_t)3072 * 2048 * 2));
  u16* wob    = (u16*)(ws + alloc((size_t)2048 * 2048 * 2));
  u16* qkvraw = (u16*)(ws + alloc((size_t)4096 * 3072 * 2));  // later reused as ytmp
  u16* qr     = (u16*)(ws + alloc((size_t)4096 * 2048 * 2));
  u16* kr     = (u16*)(ws + alloc((size_t)4096 * 512 * 2));
  u16* vt     = (u16*)(ws + alloc((size_t)4096 * 512 * 2));
  float* ctab = (float*)(ws + alloc((size_t)2048 * 64 * 4));
  float* stab = (float*)(ws + alloc((size_t)2048 * 64 * 4));
  u16* ytmp = qkvraw;  // safe: qkvraw fully consumed before attn writes

  const float sc_log2 = 0.12751744f;  // 1/sqrt(128) * log2(e)

  cvt_all<<<18432, 256, 0, stream>>>(x, wq, wk, wv, wo, xb, wqkvb, wob);
  rope_table<<<512, 256, 0, stream>>>(ctab, stab);

  // fused QKV projection: [4096,2048] x [3072,2048]^T -> [4096,3072]; 768 blocks (2/CU res.)
  gemm_2ph<0><<<dim3(24, 32), 256, 0, stream>>>(xb, wqkvb, qkvraw, 4096, 3072, 2048);

  rope_norm<16><<<16384, 256, 0, stream>>>(qkvraw, qr, ctab, stab, gq, 3072, 0, sc_log2);
  rope_norm<4><<<4096, 256, 0, stream>>>(qkvraw, kr, ctab, stab, gk, 3072, 2048, 1.0f);
  transpose_v<<<dim3(64, 4, 8), 256, 0, stream>>>(qkvraw, vt);

  attn_kernel<<<dim3(512), 512, 0, stream>>>(qr, kr, vt, ytmp);

  // output projection (f32 out): 512 blocks (2/CU)
  gemm_2ph<1><<<dim3(16, 32), 256, 0, stream>>>(ytmp, wob, out, 4096, 2048, 2048);
}